// Round 8
// baseline (601.449 us; speedup 1.0000x reference)
//
#include <hip/hip_runtime.h>
#include <hip/hip_bf16.h>

#define N_NODES 100000
#define N_EDGES 600000
#define FEAT 128
#define KTOT 256   // concat [feat | h_neigh]
#define CLS 40
#define TM 128
#define TN 128
#define KC 16
#define NBLK 391   // ceil(N_NODES/256)

__device__ __forceinline__ float h2f(unsigned short u) {
    return __uint_as_float(((unsigned)u) << 16);
}

// Load 4 consecutive float elements from a buffer that is either bf16 or f32.
__device__ __forceinline__ float4 load4(const void* base, size_t elemIdx, int isb) {
    if (isb) {
        uint2 r = *reinterpret_cast<const uint2*>((const unsigned short*)base + elemIdx);
        return make_float4(__uint_as_float(r.x << 16),
                           __uint_as_float(r.x & 0xffff0000u),
                           __uint_as_float(r.y << 16),
                           __uint_as_float(r.y & 0xffff0000u));
    } else {
        return *reinterpret_cast<const float4*>((const float*)base + elemIdx);
    }
}
__device__ __forceinline__ float loadS(const void* base, size_t i, int isb) {
    return isb ? h2f(((const unsigned short*)base)[i]) : ((const float*)base)[i];
}

// flags[0]: 1 -> indices int64, 0 -> int32
// flags[1]: 1 -> float buffers bf16, 0 -> f32
__global__ void detect_kernel(const unsigned int* __restrict__ idx_words,
                              const unsigned short* __restrict__ feat_halves,
                              int* __restrict__ flags) {
    __shared__ int any64;
    __shared__ int cnt;
    if (threadIdx.x == 0) { any64 = 0; cnt = 0; }
    __syncthreads();
    int local = 0;
    for (int i = threadIdx.x; i < 4096; i += 256) {
        if (idx_words[2 * i + 1] != 0u) any64 = 1;  // benign race
        unsigned short w = feat_halves[2 * i];      // even halves
        int e = (w >> 7) & 0xFF;                    // bf16 exponent field
        if (e >= 112 && e <= 143) local++;
    }
    atomicAdd(&cnt, local);
    __syncthreads();
    if (threadIdx.x == 0) {
        flags[0] = any64 ? 0 : 1;
        flags[1] = (cnt > 3072) ? 1 : 0;
    }
}

__device__ __forceinline__ int load_idx(const void* p, int e, int isI64) {
    return isI64 ? (int)((const long long*)p)[e] : ((const int*)p)[e];
}

__global__ void deg_kernel(const void* __restrict__ dstv,
                           const int* __restrict__ flags,
                           int* __restrict__ deg) {
    int e = blockIdx.x * blockDim.x + threadIdx.x;
    if (e >= N_EDGES) return;
    atomicAdd(&deg[load_idx(dstv, e, flags[0])], 1);
}

__global__ void bsum_kernel(const int* __restrict__ deg, int* __restrict__ bsum) {
    __shared__ int s[256];
    int gi = blockIdx.x * 256 + threadIdx.x;
    s[threadIdx.x] = (gi < N_NODES) ? deg[gi] : 0;
    __syncthreads();
    for (int st = 128; st > 0; st >>= 1) {
        if (threadIdx.x < st) s[threadIdx.x] += s[threadIdx.x + st];
        __syncthreads();
    }
    if (threadIdx.x == 0) bsum[blockIdx.x] = s[0];
}

__global__ void bscan_kernel(const int* __restrict__ bsum, int* __restrict__ boff) {
    __shared__ int s[512];
    int t = threadIdx.x;
    int v = (t < NBLK) ? bsum[t] : 0;
    s[t] = v;
    __syncthreads();
    for (int st = 1; st < 512; st <<= 1) {
        int add = (t >= st) ? s[t - st] : 0;
        __syncthreads();
        s[t] += add;
        __syncthreads();
    }
    if (t < NBLK) boff[t] = s[t] - v;
}

__global__ void rowptr_kernel(const int* __restrict__ deg,
                              const int* __restrict__ boff,
                              int* __restrict__ rowptr,
                              int* __restrict__ cursor) {
    __shared__ int s[256];
    int t = threadIdx.x;
    int gi = blockIdx.x * 256 + t;
    int v = (gi < N_NODES) ? deg[gi] : 0;
    s[t] = v;
    __syncthreads();
    for (int st = 1; st < 256; st <<= 1) {
        int add = (t >= st) ? s[t - st] : 0;
        __syncthreads();
        s[t] += add;
        __syncthreads();
    }
    if (gi < N_NODES) {
        int excl = boff[blockIdx.x] + s[t] - v;
        rowptr[gi] = excl;
        cursor[gi] = excl;
        if (gi == N_NODES - 1) rowptr[N_NODES] = excl + v;
    }
}

__global__ void fill_kernel(const void* __restrict__ srcv,
                            const void* __restrict__ dstv,
                            const int* __restrict__ flags,
                            int* __restrict__ cursor,
                            int* __restrict__ csr_src) {
    int e = blockIdx.x * blockDim.x + threadIdx.x;
    if (e >= N_EDGES) return;
    int isI64 = flags[0];
    int s = load_idx(srcv, e, isI64);
    int d = load_idx(dstv, e, isI64);
    int pos = atomicAdd(&cursor[d], 1);
    csr_src[pos] = s;
}

// t = relu([feat | mean_nbr(feat)] @ [W_self; W_neigh] + b_neigh), f32 out.
__global__ __launch_bounds__(256, 2)
void tgemm_kernel(const void* __restrict__ feat,
                  const void* __restrict__ Wself,
                  const void* __restrict__ Wneigh,
                  const void* __restrict__ bneigh,
                  const int* __restrict__ rowptr,
                  const int* __restrict__ csr_src,
                  const int* __restrict__ flags,
                  float* __restrict__ tout) {
    __shared__ float As[KC][TM + 4];  // transposed: As[k][m]
    __shared__ float Ws[KC][TN + 4];  // Ws[k][n]
    int isb = flags[1];
    int tid = threadIdx.x;
    int ty = tid >> 4, tx = tid & 15;
    int brow = blockIdx.x * TM;
    float acc[8][8];
    #pragma unroll
    for (int i = 0; i < 8; ++i)
        #pragma unroll
        for (int j = 0; j < 8; ++j) acc[i][j] = 0.f;

    for (int k0 = 0; k0 < KTOT; k0 += KC) {
        #pragma unroll
        for (int i = 0; i < 2; ++i) {
            int u = tid + 256 * i;        // 0..511
            int m = u >> 2;               // 0..127
            int kq = u & 3;
            int node = brow + m;
            int kl = kq * 4;
            int k = k0 + kl;
            float4 v = make_float4(0.f, 0.f, 0.f, 0.f);
            if (node < N_NODES) {
                if (k < FEAT) {
                    v = load4(feat, (size_t)node * FEAT + k, isb);
                } else {
                    int r0 = rowptr[node], r1 = rowptr[node + 1];
                    float4 sum = make_float4(0.f, 0.f, 0.f, 0.f);
                    for (int p = r0; p < r1; ++p) {
                        int nb = csr_src[p];
                        float4 f = load4(feat, (size_t)nb * FEAT + (k - FEAT), isb);
                        sum.x += f.x; sum.y += f.y; sum.z += f.z; sum.w += f.w;
                    }
                    float inv = 1.0f / fmaxf((float)(r1 - r0), 1.0f);
                    v = make_float4(sum.x * inv, sum.y * inv, sum.z * inv, sum.w * inv);
                }
            }
            As[kl + 0][m] = v.x;
            As[kl + 1][m] = v.y;
            As[kl + 2][m] = v.z;
            As[kl + 3][m] = v.w;
        }
        #pragma unroll
        for (int i = 0; i < 2; ++i) {
            int u = tid + 256 * i;
            int kk = u >> 5;
            int n4 = u & 31;
            int k = k0 + kk;
            float4 w = (k < FEAT)
                ? load4(Wself,  (size_t)k * FEAT + n4 * 4, isb)
                : load4(Wneigh, (size_t)(k - FEAT) * FEAT + n4 * 4, isb);
            Ws[kk][n4 * 4 + 0] = w.x;
            Ws[kk][n4 * 4 + 1] = w.y;
            Ws[kk][n4 * 4 + 2] = w.z;
            Ws[kk][n4 * 4 + 3] = w.w;
        }
        __syncthreads();
        #pragma unroll
        for (int kk = 0; kk < KC; ++kk) {
            float a[8], w[8];
            *reinterpret_cast<float4*>(&a[0]) = *reinterpret_cast<const float4*>(&As[kk][ty * 8]);
            *reinterpret_cast<float4*>(&a[4]) = *reinterpret_cast<const float4*>(&As[kk][ty * 8 + 4]);
            *reinterpret_cast<float4*>(&w[0]) = *reinterpret_cast<const float4*>(&Ws[kk][tx * 8]);
            *reinterpret_cast<float4*>(&w[4]) = *reinterpret_cast<const float4*>(&Ws[kk][tx * 8 + 4]);
            #pragma unroll
            for (int i = 0; i < 8; ++i)
                #pragma unroll
                for (int j = 0; j < 8; ++j)
                    acc[i][j] += a[i] * w[j];
        }
        __syncthreads();
    }

    float bn[8];
    #pragma unroll
    for (int j = 0; j < 8; ++j) bn[j] = loadS(bneigh, tx * 8 + j, isb);
    #pragma unroll
    for (int i = 0; i < 8; ++i) {
        int node = brow + ty * 8 + i;
        if (node < N_NODES) {
            float4 o0, o1;
            o0.x = fmaxf(acc[i][0] + bn[0], 0.f);
            o0.y = fmaxf(acc[i][1] + bn[1], 0.f);
            o0.z = fmaxf(acc[i][2] + bn[2], 0.f);
            o0.w = fmaxf(acc[i][3] + bn[3], 0.f);
            o1.x = fmaxf(acc[i][4] + bn[4], 0.f);
            o1.y = fmaxf(acc[i][5] + bn[5], 0.f);
            o1.z = fmaxf(acc[i][6] + bn[6], 0.f);
            o1.w = fmaxf(acc[i][7] + bn[7], 0.f);
            float* trow = tout + (size_t)node * FEAT + tx * 8;
            *reinterpret_cast<float4*>(trow)     = o0;
            *reinterpret_cast<float4*>(trow + 4) = o1;
        }
    }
}

// out = t @ W_pred + b_pred, f32 in/out.
__global__ void out_kernel(const float* __restrict__ t,
                           const void* __restrict__ Wpred,
                           const void* __restrict__ bpred,
                           const int* __restrict__ flags,
                           float* __restrict__ out) {
    int isb = flags[1];
    int row = blockIdx.x * blockDim.x + threadIdx.x;
    if (row >= N_NODES) return;
    float acc[CLS];
    #pragma unroll
    for (int c = 0; c < CLS; ++c) acc[c] = loadS(bpred, c, isb);
    const float* tr = t + (size_t)row * FEAT;
    #pragma unroll
    for (int k0 = 0; k0 < FEAT; k0 += 4) {
        float4 tv = *reinterpret_cast<const float4*>(tr + k0);
        float tvs[4] = {tv.x, tv.y, tv.z, tv.w};
        #pragma unroll
        for (int kk = 0; kk < 4; ++kk) {
            #pragma unroll
            for (int cq = 0; cq < 10; ++cq) {
                float4 w = load4(Wpred, (size_t)(k0 + kk) * CLS + cq * 4, isb);
                acc[cq * 4 + 0] += tvs[kk] * w.x;
                acc[cq * 4 + 1] += tvs[kk] * w.y;
                acc[cq * 4 + 2] += tvs[kk] * w.z;
                acc[cq * 4 + 3] += tvs[kk] * w.w;
            }
        }
    }
    float* orow = out + (size_t)row * CLS;
    #pragma unroll
    for (int g = 0; g < 10; ++g) {
        float4 o;
        o.x = acc[g * 4 + 0];
        o.y = acc[g * 4 + 1];
        o.z = acc[g * 4 + 2];
        o.w = acc[g * 4 + 3];
        *reinterpret_cast<float4*>(orow + g * 4) = o;
    }
}

extern "C" void kernel_launch(void* const* d_in, const int* in_sizes, int n_in,
                              void* d_out, int out_size, void* d_ws, size_t ws_size,
                              hipStream_t stream) {
    // Inputs in setup_inputs() dict (insertion) order, per harness docs.
    const void* feat   = d_in[0];
    const void* src    = d_in[1];
    const void* dst    = d_in[2];
    const void* Wself  = d_in[3];
    const void* Wneigh = d_in[4];
    const void* bneigh = d_in[5];
    const void* Wpred  = d_in[6];
    const void* bpred  = d_in[7];

    // Output dtype = reference output dtype = FLOAT32 (the round-0 bf16
    // inference was wrong: the "(bf16, ...)" label is a hardcoded string).
    // Layout: [ out : 100000*40 f32 | t : 100000*128 f32 ]
    float* obuf = (float*)d_out;
    float* tbuf = obuf + (size_t)N_NODES * CLS;

    int* flags   = (int*)d_ws;                 // [16]
    int* deg     = flags + 16;                 // [N]
    int* bsum    = deg + N_NODES;              // [512]
    int* boff    = bsum + 512;                 // [512]
    int* rowptr  = boff + 512;                 // [N+1]
    int* cursor  = rowptr + (N_NODES + 1);     // [N]
    int* csr_src = cursor + N_NODES;           // [E]

    hipMemsetAsync(deg, 0, N_NODES * sizeof(int), stream);

    detect_kernel<<<1, 256, 0, stream>>>((const unsigned int*)src,
                                         (const unsigned short*)feat, flags);
    deg_kernel<<<(N_EDGES + 255) / 256, 256, 0, stream>>>(dst, flags, deg);
    bsum_kernel<<<NBLK, 256, 0, stream>>>(deg, bsum);
    bscan_kernel<<<1, 512, 0, stream>>>(bsum, boff);
    rowptr_kernel<<<NBLK, 256, 0, stream>>>(deg, boff, rowptr, cursor);
    fill_kernel<<<(N_EDGES + 255) / 256, 256, 0, stream>>>(src, dst, flags, cursor, csr_src);
    tgemm_kernel<<<(N_NODES + TM - 1) / TM, 256, 0, stream>>>(
        feat, Wself, Wneigh, bneigh, rowptr, csr_src, flags, tbuf);
    out_kernel<<<NBLK, 256, 0, stream>>>(tbuf, Wpred, bpred, flags, obuf);
}

// Round 9
// 303.952 us; speedup vs baseline: 1.9788x; 1.9788x over previous
//
#include <hip/hip_runtime.h>

#define N_NODES 100000
#define N_EDGES 600000
#define FEAT 128
#define KTOT 256   // concat [feat | h_neigh]
#define CLS 40
#define TM 128
#define KC 16
#define NBLK 391   // ceil(N_NODES/256)

// ---------- CSR build ----------
__global__ void deg_kernel(const int* __restrict__ dst, int* __restrict__ deg) {
    int e = blockIdx.x * 256 + threadIdx.x;
    if (e < N_EDGES) atomicAdd(&deg[dst[e]], 1);
}

__global__ void bsum_kernel(const int* __restrict__ deg, int* __restrict__ bsum) {
    __shared__ int s[256];
    int gi = blockIdx.x * 256 + threadIdx.x;
    s[threadIdx.x] = (gi < N_NODES) ? deg[gi] : 0;
    __syncthreads();
    for (int st = 128; st > 0; st >>= 1) {
        if (threadIdx.x < st) s[threadIdx.x] += s[threadIdx.x + st];
        __syncthreads();
    }
    if (threadIdx.x == 0) bsum[blockIdx.x] = s[0];
}

__global__ void bscan_kernel(const int* __restrict__ bsum, int* __restrict__ boff) {
    __shared__ int s[512];
    int t = threadIdx.x;
    int v = (t < NBLK) ? bsum[t] : 0;
    s[t] = v;
    __syncthreads();
    for (int st = 1; st < 512; st <<= 1) {
        int add = (t >= st) ? s[t - st] : 0;
        __syncthreads();
        s[t] += add;
        __syncthreads();
    }
    if (t < NBLK) boff[t] = s[t] - v;
}

__global__ void rowptr_kernel(const int* __restrict__ deg,
                              const int* __restrict__ boff,
                              int* __restrict__ rowptr,
                              int* __restrict__ cursor) {
    __shared__ int s[256];
    int t = threadIdx.x;
    int gi = blockIdx.x * 256 + t;
    int v = (gi < N_NODES) ? deg[gi] : 0;
    s[t] = v;
    __syncthreads();
    for (int st = 1; st < 256; st <<= 1) {
        int add = (t >= st) ? s[t - st] : 0;
        __syncthreads();
        s[t] += add;
        __syncthreads();
    }
    if (gi < N_NODES) {
        int excl = boff[blockIdx.x] + s[t] - v;
        rowptr[gi] = excl;
        cursor[gi] = excl;
        if (gi == N_NODES - 1) rowptr[N_NODES] = excl + v;
    }
}

__global__ void fill_kernel(const int* __restrict__ src, const int* __restrict__ dst,
                            int* __restrict__ cursor, int* __restrict__ csr_src) {
    int e = blockIdx.x * 256 + threadIdx.x;
    if (e >= N_EDGES) return;
    int pos = atomicAdd(&cursor[dst[e]], 1);
    csr_src[pos] = src[e];
}

// ---------- h_neigh materialization: one wave per node ----------
// lane l accumulates feats [2l, 2l+1]; 512B coalesced per neighbor row.
__global__ __launch_bounds__(256, 4)
void hn_kernel(const float* __restrict__ feat,
               const int* __restrict__ rowptr,
               const int* __restrict__ csr_src,
               float* __restrict__ hn) {
    int node = blockIdx.x * 4 + (threadIdx.x >> 6);
    int lane = threadIdx.x & 63;
    if (node >= N_NODES) return;
    int r0 = rowptr[node], r1 = rowptr[node + 1];
    float sx = 0.f, sy = 0.f;
    for (int p = r0; p < r1; ++p) {
        int nb = csr_src[p];
        float2 f = *reinterpret_cast<const float2*>(feat + (size_t)nb * FEAT + lane * 2);
        sx += f.x; sy += f.y;
    }
    float inv = 1.0f / fmaxf((float)(r1 - r0), 1.0f);
    float2 o; o.x = sx * inv; o.y = sy * inv;
    *reinterpret_cast<float2*>(hn + (size_t)node * FEAT + lane * 2) = o;
}

// ---------- t = relu([feat | hn] @ [W_self; W_neigh] + b_neigh) ----------
// Dense 128x128 tile, 256 threads, 8x8 register tile.
// N-cols per thread: {tx*4..tx*4+3, 64+tx*4..64+tx*4+3}  (2-way LDS bank alias = free)
__global__ __launch_bounds__(256, 2)
void tgemm_kernel(const float* __restrict__ feat,
                  const float* __restrict__ hn,
                  const float* __restrict__ Wself,
                  const float* __restrict__ Wneigh,
                  const float* __restrict__ bneigh,
                  float* __restrict__ tout) {
    __shared__ float As[KC][TM + 4];   // transposed: As[k][m]
    __shared__ float Ws[KC][132];      // Ws[k][n]
    int tid = threadIdx.x;
    int ty = tid >> 4, tx = tid & 15;
    int brow = blockIdx.x * TM;
    float acc[8][8];
    #pragma unroll
    for (int i = 0; i < 8; ++i)
        #pragma unroll
        for (int j = 0; j < 8; ++j) acc[i][j] = 0.f;

    for (int k0 = 0; k0 < KTOT; k0 += KC) {
        // Stage A chunk (linear loads from feat or hn).
        #pragma unroll
        for (int i = 0; i < 2; ++i) {
            int u = tid + 256 * i;        // 0..511
            int m = u >> 2;               // 0..127
            int kq = u & 3;
            int node = brow + m;
            int kl = kq * 4;
            int k = k0 + kl;
            float4 v = make_float4(0.f, 0.f, 0.f, 0.f);
            if (node < N_NODES) {
                const float* base = (k < FEAT)
                    ? feat + (size_t)node * FEAT + k
                    : hn   + (size_t)node * FEAT + (k - FEAT);
                v = *reinterpret_cast<const float4*>(base);
            }
            As[kl + 0][m] = v.x;
            As[kl + 1][m] = v.y;
            As[kl + 2][m] = v.z;
            As[kl + 3][m] = v.w;
        }
        // Stage W chunk.
        #pragma unroll
        for (int i = 0; i < 2; ++i) {
            int u = tid + 256 * i;
            int kk = u >> 5;
            int n4 = u & 31;
            int k = k0 + kk;
            const float* wsrc = (k < FEAT) ? (Wself + (size_t)k * FEAT)
                                           : (Wneigh + (size_t)(k - FEAT) * FEAT);
            *reinterpret_cast<float4*>(&Ws[kk][n4 * 4]) =
                *reinterpret_cast<const float4*>(wsrc + n4 * 4);
        }
        __syncthreads();
        #pragma unroll
        for (int kk = 0; kk < KC; ++kk) {
            float a[8], w[8];
            *reinterpret_cast<float4*>(&a[0]) = *reinterpret_cast<const float4*>(&As[kk][ty * 8]);
            *reinterpret_cast<float4*>(&a[4]) = *reinterpret_cast<const float4*>(&As[kk][ty * 8 + 4]);
            *reinterpret_cast<float4*>(&w[0]) = *reinterpret_cast<const float4*>(&Ws[kk][tx * 4]);
            *reinterpret_cast<float4*>(&w[4]) = *reinterpret_cast<const float4*>(&Ws[kk][64 + tx * 4]);
            #pragma unroll
            for (int i = 0; i < 8; ++i)
                #pragma unroll
                for (int j = 0; j < 8; ++j)
                    acc[i][j] += a[i] * w[j];
        }
        __syncthreads();
    }

    float bn[8];
    #pragma unroll
    for (int j = 0; j < 4; ++j) bn[j]     = bneigh[tx * 4 + j];
    #pragma unroll
    for (int j = 0; j < 4; ++j) bn[4 + j] = bneigh[64 + tx * 4 + j];
    #pragma unroll
    for (int i = 0; i < 8; ++i) {
        int node = brow + ty * 8 + i;
        if (node < N_NODES) {
            float4 o0, o1;
            o0.x = fmaxf(acc[i][0] + bn[0], 0.f);
            o0.y = fmaxf(acc[i][1] + bn[1], 0.f);
            o0.z = fmaxf(acc[i][2] + bn[2], 0.f);
            o0.w = fmaxf(acc[i][3] + bn[3], 0.f);
            o1.x = fmaxf(acc[i][4] + bn[4], 0.f);
            o1.y = fmaxf(acc[i][5] + bn[5], 0.f);
            o1.z = fmaxf(acc[i][6] + bn[6], 0.f);
            o1.w = fmaxf(acc[i][7] + bn[7], 0.f);
            float* trow = tout + (size_t)node * FEAT;
            *reinterpret_cast<float4*>(trow + tx * 4)      = o0;
            *reinterpret_cast<float4*>(trow + 64 + tx * 4) = o1;
        }
    }
}

// ---------- out = t @ W_pred + b_pred ----------
// 256 rows/block; t staged transposed through LDS (coalesced); Wpred in LDS.
__global__ __launch_bounds__(256, 4)
void out_kernel(const float* __restrict__ t,
                const float* __restrict__ Wpred,
                const float* __restrict__ bpred,
                float* __restrict__ out) {
    __shared__ float Ts[KC][256 + 4];
    __shared__ float Wp[FEAT * CLS];   // 5120 f = 20.5 KB
    int tid = threadIdx.x;
    int brow = blockIdx.x * 256;

    for (int i = tid; i < FEAT * CLS; i += 256) Wp[i] = Wpred[i];

    float acc[CLS];
    #pragma unroll
    for (int c = 0; c < CLS; ++c) acc[c] = bpred[c];

    for (int k0 = 0; k0 < FEAT; k0 += KC) {
        #pragma unroll
        for (int i = 0; i < 4; ++i) {
            int u = tid + 256 * i;        // 0..1023
            int m = u >> 2;               // 0..255
            int kq = u & 3;
            int row = brow + m;
            int kl = kq * 4;
            float4 v = make_float4(0.f, 0.f, 0.f, 0.f);
            if (row < N_NODES)
                v = *reinterpret_cast<const float4*>(t + (size_t)row * FEAT + k0 + kl);
            Ts[kl + 0][m] = v.x;
            Ts[kl + 1][m] = v.y;
            Ts[kl + 2][m] = v.z;
            Ts[kl + 3][m] = v.w;
        }
        __syncthreads();
        #pragma unroll
        for (int kk = 0; kk < KC; ++kk) {
            float a = Ts[kk][tid];
            const float* wrow = &Wp[(k0 + kk) * CLS];
            #pragma unroll
            for (int cq = 0; cq < 10; ++cq) {
                float4 w = *reinterpret_cast<const float4*>(wrow + cq * 4);  // broadcast
                acc[cq * 4 + 0] += a * w.x;
                acc[cq * 4 + 1] += a * w.y;
                acc[cq * 4 + 2] += a * w.z;
                acc[cq * 4 + 3] += a * w.w;
            }
        }
        __syncthreads();
    }

    int row = brow + tid;
    if (row < N_NODES) {
        float* orow = out + (size_t)row * CLS;
        #pragma unroll
        for (int g = 0; g < 10; ++g) {
            float4 o;
            o.x = acc[g * 4 + 0];
            o.y = acc[g * 4 + 1];
            o.z = acc[g * 4 + 2];
            o.w = acc[g * 4 + 3];
            *reinterpret_cast<float4*>(orow + g * 4) = o;
        }
    }
}

extern "C" void kernel_launch(void* const* d_in, const int* in_sizes, int n_in,
                              void* d_out, int out_size, void* d_ws, size_t ws_size,
                              hipStream_t stream) {
    const float* feat   = (const float*)d_in[0];
    const int*   src    = (const int*)d_in[1];
    const int*   dst    = (const int*)d_in[2];
    const float* Wself  = (const float*)d_in[3];
    const float* Wneigh = (const float*)d_in[4];
    const float* bneigh = (const float*)d_in[5];
    const float* Wpred  = (const float*)d_in[6];
    const float* bpred  = (const float*)d_in[7];

    // d_out layout: [ out : 100000*40 f32 | t : 100000*128 f32 ]
    float* obuf = (float*)d_out;
    float* tbuf = obuf + (size_t)N_NODES * CLS;
    // h_neigh is materialized into the t-region, then overwritten by t
    // (each tgemm block reads hn only for rows it itself later writes).
    float* hn = tbuf;

    int* deg     = (int*)d_ws;                 // [N]
    int* bsum    = deg + N_NODES;              // [512]
    int* boff    = bsum + 512;                 // [512]
    int* rowptr  = boff + 512;                 // [N+1]
    int* cursor  = rowptr + (N_NODES + 1);     // [N]
    int* csr_src = cursor + N_NODES;           // [E]

    hipMemsetAsync(deg, 0, N_NODES * sizeof(int), stream);

    deg_kernel<<<(N_EDGES + 255) / 256, 256, 0, stream>>>(dst, deg);
    bsum_kernel<<<NBLK, 256, 0, stream>>>(deg, bsum);
    bscan_kernel<<<1, 512, 0, stream>>>(bsum, boff);
    rowptr_kernel<<<NBLK, 256, 0, stream>>>(deg, boff, rowptr, cursor);
    fill_kernel<<<(N_EDGES + 255) / 256, 256, 0, stream>>>(src, dst, cursor, csr_src);
    hn_kernel<<<(N_NODES + 3) / 4, 256, 0, stream>>>(feat, rowptr, csr_src, hn);
    tgemm_kernel<<<(N_NODES + TM - 1) / TM, 256, 0, stream>>>(
        feat, hn, Wself, Wneigh, bneigh, tbuf);
    out_kernel<<<NBLK, 256, 0, stream>>>(tbuf, Wpred, bpred, obuf);
}

// Round 10
// 239.555 us; speedup vs baseline: 2.5107x; 1.2688x over previous
//
#include <hip/hip_runtime.h>
#include <hip/hip_bf16.h>

#define N_NODES 100000
#define N_EDGES 600000
#define FEAT 128
#define KTOT 256   // concat [feat | h_neigh]
#define CLS 40
#define TM 128
#define NBLK 391   // ceil(N_NODES/256)

typedef __attribute__((ext_vector_type(8))) short short8;
typedef __attribute__((ext_vector_type(4))) float f32x4;

__device__ __forceinline__ unsigned short f2b(float f) {
    __hip_bfloat16 h = __float2bfloat16(f);
    return *reinterpret_cast<unsigned short*>(&h);
}

// ---------- CSR build ----------
__global__ void deg_kernel(const int* __restrict__ dst, int* __restrict__ deg) {
    int e = blockIdx.x * 256 + threadIdx.x;
    if (e < N_EDGES) atomicAdd(&deg[dst[e]], 1);
}

__global__ void bsum_kernel(const int* __restrict__ deg, int* __restrict__ bsum) {
    __shared__ int s[256];
    int gi = blockIdx.x * 256 + threadIdx.x;
    s[threadIdx.x] = (gi < N_NODES) ? deg[gi] : 0;
    __syncthreads();
    for (int st = 128; st > 0; st >>= 1) {
        if (threadIdx.x < st) s[threadIdx.x] += s[threadIdx.x + st];
        __syncthreads();
    }
    if (threadIdx.x == 0) bsum[blockIdx.x] = s[0];
}

__global__ void bscan_kernel(const int* __restrict__ bsum, int* __restrict__ boff) {
    __shared__ int s[512];
    int t = threadIdx.x;
    int v = (t < NBLK) ? bsum[t] : 0;
    s[t] = v;
    __syncthreads();
    for (int st = 1; st < 512; st <<= 1) {
        int add = (t >= st) ? s[t - st] : 0;
        __syncthreads();
        s[t] += add;
        __syncthreads();
    }
    if (t < NBLK) boff[t] = s[t] - v;
}

__global__ void rowptr_kernel(const int* __restrict__ deg,
                              const int* __restrict__ boff,
                              int* __restrict__ rowptr,
                              int* __restrict__ cursor) {
    __shared__ int s[256];
    int t = threadIdx.x;
    int gi = blockIdx.x * 256 + t;
    int v = (gi < N_NODES) ? deg[gi] : 0;
    s[t] = v;
    __syncthreads();
    for (int st = 1; st < 256; st <<= 1) {
        int add = (t >= st) ? s[t - st] : 0;
        __syncthreads();
        s[t] += add;
        __syncthreads();
    }
    if (gi < N_NODES) {
        int excl = boff[blockIdx.x] + s[t] - v;
        rowptr[gi] = excl;
        cursor[gi] = excl;
        if (gi == N_NODES - 1) rowptr[N_NODES] = excl + v;
    }
}

__global__ void fill_kernel(const int* __restrict__ src, const int* __restrict__ dst,
                            int* __restrict__ cursor, int* __restrict__ csr_src) {
    int e = blockIdx.x * 256 + threadIdx.x;
    if (e >= N_EDGES) return;
    int pos = atomicAdd(&cursor[dst[e]], 1);
    csr_src[pos] = src[e];
}

// ---------- h_neigh materialization: one wave per node ----------
__global__ __launch_bounds__(256, 4)
void hn_kernel(const float* __restrict__ feat,
               const int* __restrict__ rowptr,
               const int* __restrict__ csr_src,
               float* __restrict__ hn) {
    int node = blockIdx.x * 4 + (threadIdx.x >> 6);
    int lane = threadIdx.x & 63;
    if (node >= N_NODES) return;
    int r0 = rowptr[node], r1 = rowptr[node + 1];
    float sx = 0.f, sy = 0.f;
    for (int p = r0; p < r1; ++p) {
        int nb = csr_src[p];
        float2 f = *reinterpret_cast<const float2*>(feat + (size_t)nb * FEAT + lane * 2);
        sx += f.x; sy += f.y;
    }
    float inv = 1.0f / fmaxf((float)(r1 - r0), 1.0f);
    float2 o; o.x = sx * inv; o.y = sy * inv;
    *reinterpret_cast<float2*>(hn + (size_t)node * FEAT + lane * 2) = o;
}

// ---------- t = relu([feat|hn] @ [W_self;W_neigh] + b_neigh)  — bf16 MFMA ----------
// 128x128 tile, 4 waves (2x2), each wave 64x64 = 4x4 frags of 16x16x32.
// A in LDS [128 rows][40 bf16] (80B stride), B transposed [128 cols][36 bf16] (72B).
#define ASTR 40
#define BSTR 36
__global__ __launch_bounds__(256, 2)
void tgemm_kernel(const float* __restrict__ feat,
                  const float* __restrict__ hn,
                  const float* __restrict__ Wself,
                  const float* __restrict__ Wneigh,
                  const float* __restrict__ bneigh,
                  float* __restrict__ tout) {
    __shared__ __align__(16) unsigned short Asb[128 * ASTR];
    __shared__ __align__(16) unsigned short Bsb[128 * BSTR];

    int tid  = threadIdx.x;
    int lane = tid & 63;
    int w    = tid >> 6;        // wave 0..3
    int wm   = w >> 1;          // 0..1  (row half)
    int wn   = w & 1;           // 0..1  (col half)
    int lr   = lane & 15;       // fragment row/col index
    int lq   = lane >> 4;       // 0..3  (k-group / out row group)
    int brow = blockIdx.x * TM;

    f32x4 acc[4][4];
    #pragma unroll
    for (int i = 0; i < 4; ++i)
        #pragma unroll
        for (int j = 0; j < 4; ++j) acc[i][j] = (f32x4){0.f, 0.f, 0.f, 0.f};

    for (int k0 = 0; k0 < KTOT; k0 += 32) {
        // ---- Stage A: 128 rows x 32 k, f32 -> bf16 ----
        #pragma unroll
        for (int i = 0; i < 4; ++i) {
            int u   = tid + 256 * i;      // 0..1023
            int row = u >> 3;             // 0..127
            int c4  = u & 7;              // float4 index (k-local)
            int node = brow + row;
            int k = k0 + c4 * 4;
            float4 v = make_float4(0.f, 0.f, 0.f, 0.f);
            if (node < N_NODES) {
                const float* base = (k < FEAT)
                    ? feat + (size_t)node * FEAT + k
                    : hn   + (size_t)node * FEAT + (k - FEAT);
                v = *reinterpret_cast<const float4*>(base);
            }
            ushort4 p;
            p.x = f2b(v.x); p.y = f2b(v.y); p.z = f2b(v.z); p.w = f2b(v.w);
            *reinterpret_cast<ushort4*>(&Asb[row * ASTR + c4 * 4]) = p;
        }
        // ---- Stage B transposed: Bsb[n][k-local], 4 strided coalesced reads ----
        #pragma unroll
        for (int i = 0; i < 4; ++i) {
            int u  = tid + 256 * i;       // 0..1023
            int n  = u & 127;
            int kq = u >> 7;              // 0..7 (k-local group of 4)
            int k  = k0 + kq * 4;
            const float* base = ((k < FEAT) ? (Wself + (size_t)k * FEAT)
                                            : (Wneigh + (size_t)(k - FEAT) * FEAT)) + n;
            ushort4 p;
            p.x = f2b(base[0]);
            p.y = f2b(base[FEAT]);
            p.z = f2b(base[2 * FEAT]);
            p.w = f2b(base[3 * FEAT]);
            *reinterpret_cast<ushort4*>(&Bsb[n * BSTR + kq * 4]) = p;
        }
        __syncthreads();

        // ---- Fragments + 16 MFMA ----
        short8 af[4], bf[4];
        #pragma unroll
        for (int mi = 0; mi < 4; ++mi) {
            int row = wm * 64 + mi * 16 + lr;
            *reinterpret_cast<uint4*>(&af[mi]) =
                *reinterpret_cast<const uint4*>(&Asb[row * ASTR + lq * 8]);
        }
        #pragma unroll
        for (int ni = 0; ni < 4; ++ni) {
            int col = wn * 64 + ni * 16 + lr;
            const unsigned short* bp = &Bsb[col * BSTR + lq * 8];
            *reinterpret_cast<uint2*>(&bf[ni]) = *reinterpret_cast<const uint2*>(bp);
            *(reinterpret_cast<uint2*>(&bf[ni]) + 1) = *reinterpret_cast<const uint2*>(bp + 4);
        }
        #pragma unroll
        for (int mi = 0; mi < 4; ++mi)
            #pragma unroll
            for (int ni = 0; ni < 4; ++ni)
                acc[mi][ni] = __builtin_amdgcn_mfma_f32_16x16x32_bf16(
                    af[mi], bf[ni], acc[mi][ni], 0, 0, 0);
        __syncthreads();
    }

    // ---- Epilogue: bias + ReLU + store (D: col=lane&15, row=(lane>>4)*4+reg) ----
    #pragma unroll
    for (int ni = 0; ni < 4; ++ni) {
        int col = wn * 64 + ni * 16 + lr;
        float bn = bneigh[col];
        #pragma unroll
        for (int mi = 0; mi < 4; ++mi) {
            int row0 = brow + wm * 64 + mi * 16 + lq * 4;
            #pragma unroll
            for (int r = 0; r < 4; ++r) {
                int row = row0 + r;
                if (row < N_NODES) {
                    float v = acc[mi][ni][r] + bn;
                    tout[(size_t)row * FEAT + col] = v > 0.f ? v : 0.f;
                }
            }
        }
    }
}

// ---------- out = t @ W_pred + b_pred ----------
__global__ __launch_bounds__(256, 4)
void out_kernel(const float* __restrict__ t,
                const float* __restrict__ Wpred,
                const float* __restrict__ bpred,
                float* __restrict__ out) {
    __shared__ float Ts[16][256 + 4];
    __shared__ float Wp[FEAT * CLS];
    int tid = threadIdx.x;
    int brow = blockIdx.x * 256;

    for (int i = tid; i < FEAT * CLS; i += 256) Wp[i] = Wpred[i];

    float acc[CLS];
    #pragma unroll
    for (int c = 0; c < CLS; ++c) acc[c] = bpred[c];

    for (int k0 = 0; k0 < FEAT; k0 += 16) {
        #pragma unroll
        for (int i = 0; i < 4; ++i) {
            int u = tid + 256 * i;        // 0..1023
            int m = u >> 2;               // 0..255
            int kq = u & 3;
            int row = brow + m;
            int kl = kq * 4;
            float4 v = make_float4(0.f, 0.f, 0.f, 0.f);
            if (row < N_NODES)
                v = *reinterpret_cast<const float4*>(t + (size_t)row * FEAT + k0 + kl);
            Ts[kl + 0][m] = v.x;
            Ts[kl + 1][m] = v.y;
            Ts[kl + 2][m] = v.z;
            Ts[kl + 3][m] = v.w;
        }
        __syncthreads();
        #pragma unroll
        for (int kk = 0; kk < 16; ++kk) {
            float a = Ts[kk][tid];
            const float* wrow = &Wp[(k0 + kk) * CLS];
            #pragma unroll
            for (int cq = 0; cq < 10; ++cq) {
                float4 wv = *reinterpret_cast<const float4*>(wrow + cq * 4);
                acc[cq * 4 + 0] += a * wv.x;
                acc[cq * 4 + 1] += a * wv.y;
                acc[cq * 4 + 2] += a * wv.z;
                acc[cq * 4 + 3] += a * wv.w;
            }
        }
        __syncthreads();
    }

    int row = brow + tid;
    if (row < N_NODES) {
        float* orow = out + (size_t)row * CLS;
        #pragma unroll
        for (int g = 0; g < 10; ++g) {
            float4 o;
            o.x = acc[g * 4 + 0];
            o.y = acc[g * 4 + 1];
            o.z = acc[g * 4 + 2];
            o.w = acc[g * 4 + 3];
            *reinterpret_cast<float4*>(orow + g * 4) = o;
        }
    }
}

extern "C" void kernel_launch(void* const* d_in, const int* in_sizes, int n_in,
                              void* d_out, int out_size, void* d_ws, size_t ws_size,
                              hipStream_t stream) {
    const float* feat   = (const float*)d_in[0];
    const int*   src    = (const int*)d_in[1];
    const int*   dst    = (const int*)d_in[2];
    const float* Wself  = (const float*)d_in[3];
    const float* Wneigh = (const float*)d_in[4];
    const float* bneigh = (const float*)d_in[5];
    const float* Wpred  = (const float*)d_in[6];
    const float* bpred  = (const float*)d_in[7];

    // d_out layout: [ out : 100000*40 f32 | t : 100000*128 f32 ]
    float* obuf = (float*)d_out;
    float* tbuf = obuf + (size_t)N_NODES * CLS;
    float* hn = tbuf;   // hn materialized in t-region, overwritten per-row by tgemm

    int* deg     = (int*)d_ws;                 // [N]
    int* bsum    = deg + N_NODES;              // [512]
    int* boff    = bsum + 512;                 // [512]
    int* rowptr  = boff + 512;                 // [N+1]
    int* cursor  = rowptr + (N_NODES + 1);     // [N]
    int* csr_src = cursor + N_NODES;           // [E]

    hipMemsetAsync(deg, 0, N_NODES * sizeof(int), stream);

    deg_kernel<<<(N_EDGES + 255) / 256, 256, 0, stream>>>(dst, deg);
    bsum_kernel<<<NBLK, 256, 0, stream>>>(deg, bsum);
    bscan_kernel<<<1, 512, 0, stream>>>(bsum, boff);
    rowptr_kernel<<<NBLK, 256, 0, stream>>>(deg, boff, rowptr, cursor);
    fill_kernel<<<(N_EDGES + 255) / 256, 256, 0, stream>>>(src, dst, cursor, csr_src);
    hn_kernel<<<(N_NODES + 3) / 4, 256, 0, stream>>>(feat, rowptr, csr_src, hn);
    tgemm_kernel<<<(N_NODES + TM - 1) / TM, 256, 0, stream>>>(
        feat, hn, Wself, Wneigh, bneigh, tbuf);
    out_kernel<<<NBLK, 256, 0, stream>>>(tbuf, Wpred, bpred, obuf);
}

// Round 12
// 207.626 us; speedup vs baseline: 2.8968x; 1.1538x over previous
//
#include <hip/hip_runtime.h>
#include <hip/hip_bf16.h>

#define N_NODES 100000
#define N_EDGES 600000
#define FEAT 128
#define KTOT 256
#define CLS 40
#define TM 128
#define NBLK 391   // ceil(N_NODES/256)

typedef __attribute__((ext_vector_type(8))) short short8;
typedef __attribute__((ext_vector_type(4))) float f32x4;

__device__ __forceinline__ unsigned short f2b(float f) {
    __hip_bfloat16 h = __float2bfloat16(f);
    return *reinterpret_cast<unsigned short*>(&h);
}
__device__ __forceinline__ float b2f(unsigned int u16) {
    return __uint_as_float(u16 << 16);
}

// ---------- CSR build ----------
__global__ void deg_kernel(const int* __restrict__ dst, int* __restrict__ deg) {
    int e = blockIdx.x * 256 + threadIdx.x;
    if (e < N_EDGES) atomicAdd(&deg[dst[e]], 1);
}

__global__ void bsum_kernel(const int* __restrict__ deg, int* __restrict__ bsum) {
    __shared__ int s[256];
    int gi = blockIdx.x * 256 + threadIdx.x;
    s[threadIdx.x] = (gi < N_NODES) ? deg[gi] : 0;
    __syncthreads();
    for (int st = 128; st > 0; st >>= 1) {
        if (threadIdx.x < st) s[threadIdx.x] += s[threadIdx.x + st];
        __syncthreads();
    }
    if (threadIdx.x == 0) bsum[blockIdx.x] = s[0];
}

__global__ void bscan_kernel(const int* __restrict__ bsum, int* __restrict__ boff) {
    __shared__ int s[512];
    int t = threadIdx.x;
    int v = (t < NBLK) ? bsum[t] : 0;
    s[t] = v;
    __syncthreads();
    for (int st = 1; st < 512; st <<= 1) {
        int add = (t >= st) ? s[t - st] : 0;
        __syncthreads();
        s[t] += add;
        __syncthreads();
    }
    if (t < NBLK) boff[t] = s[t] - v;
}

__global__ void rowptr_kernel(const int* __restrict__ deg,
                              const int* __restrict__ boff,
                              int* __restrict__ rowptr,
                              int* __restrict__ cursor) {
    __shared__ int s[256];
    int t = threadIdx.x;
    int gi = blockIdx.x * 256 + t;
    int v = (gi < N_NODES) ? deg[gi] : 0;
    s[t] = v;
    __syncthreads();
    for (int st = 1; st < 256; st <<= 1) {
        int add = (t >= st) ? s[t - st] : 0;
        __syncthreads();
        s[t] += add;
        __syncthreads();
    }
    if (gi < N_NODES) {
        int excl = boff[blockIdx.x] + s[t] - v;
        rowptr[gi] = excl;
        cursor[gi] = excl;
        if (gi == N_NODES - 1) rowptr[N_NODES] = excl + v;
    }
}

__global__ void fill_kernel(const int* __restrict__ src, const int* __restrict__ dst,
                            int* __restrict__ cursor, int* __restrict__ csr_src) {
    int e = blockIdx.x * 256 + threadIdx.x;
    if (e >= N_EDGES) return;
    int pos = atomicAdd(&cursor[dst[e]], 1);
    csr_src[pos] = src[e];
}

// ---------- feat f32 -> bf16 ----------
__global__ __launch_bounds__(256, 8)
void feat2bf_kernel(const float* __restrict__ f, unsigned short* __restrict__ o) {
    size_t i = ((size_t)blockIdx.x * 256 + threadIdx.x) * 8;
    float4 a = *reinterpret_cast<const float4*>(f + i);
    float4 b = *reinterpret_cast<const float4*>(f + i + 4);
    ushort4 p0, p1;
    p0.x = f2b(a.x); p0.y = f2b(a.y); p0.z = f2b(a.z); p0.w = f2b(a.w);
    p1.x = f2b(b.x); p1.y = f2b(b.y); p1.z = f2b(b.z); p1.w = f2b(b.w);
    uint4 q;
    q.x = (unsigned)p0.x | ((unsigned)p0.y << 16);
    q.y = (unsigned)p0.z | ((unsigned)p0.w << 16);
    q.z = (unsigned)p1.x | ((unsigned)p1.y << 16);
    q.w = (unsigned)p1.z | ((unsigned)p1.w << 16);
    *reinterpret_cast<uint4*>(o + i) = q;
}

// ---------- h_neigh gather in bf16: one wave per node, 256B per row ----------
__global__ __launch_bounds__(256, 8)
void hnb_kernel(const unsigned short* __restrict__ featb,
                const int* __restrict__ rowptr,
                const int* __restrict__ csr_src,
                unsigned short* __restrict__ hnb) {
    int node = blockIdx.x * 4 + (threadIdx.x >> 6);
    int lane = threadIdx.x & 63;
    if (node >= N_NODES) return;
    int r0 = rowptr[node], r1 = rowptr[node + 1];
    float sx = 0.f, sy = 0.f;
    for (int p = r0; p < r1; ++p) {
        int nb = csr_src[p];
        unsigned int v = *reinterpret_cast<const unsigned int*>(
            featb + (size_t)nb * FEAT + lane * 2);
        sx += b2f(v & 0xffffu);
        sy += b2f(v >> 16);
    }
    float inv = 1.0f / fmaxf((float)(r1 - r0), 1.0f);
    unsigned int o = (unsigned)f2b(sx * inv) | ((unsigned)f2b(sy * inv) << 16);
    *reinterpret_cast<unsigned int*>(hnb + (size_t)node * FEAT + lane * 2) = o;
}

// f32 fallback gather (small-ws tier)
__global__ __launch_bounds__(256, 4)
void hn_kernel(const float* __restrict__ feat,
               const int* __restrict__ rowptr,
               const int* __restrict__ csr_src,
               float* __restrict__ hn) {
    int node = blockIdx.x * 4 + (threadIdx.x >> 6);
    int lane = threadIdx.x & 63;
    if (node >= N_NODES) return;
    int r0 = rowptr[node], r1 = rowptr[node + 1];
    float sx = 0.f, sy = 0.f;
    for (int p = r0; p < r1; ++p) {
        int nb = csr_src[p];
        float2 f = *reinterpret_cast<const float2*>(feat + (size_t)nb * FEAT + lane * 2);
        sx += f.x; sy += f.y;
    }
    float inv = 1.0f / fmaxf((float)(r1 - r0), 1.0f);
    float2 o; o.x = sx * inv; o.y = sy * inv;
    *reinterpret_cast<float2*>(hn + (size_t)node * FEAT + lane * 2) = o;
}

// ---------- fused: t = relu([feat|hn]@[Ws;Wn]+bn);  out = t@Wp + bp ----------
#define ASTR 40
#define BSTR 36
#define A2STR 136
// smem (bytes): [0,10240) Asb | [10240,19456) Bsb | phase2: [0,34816) A2 | [34816,47872) WpT
template <int BF16IN>
__global__ __launch_bounds__(256, 2)
void tgemm_kernel(const float* __restrict__ feat,
                  const float* __restrict__ hn,
                  const unsigned short* __restrict__ featb,
                  const unsigned short* __restrict__ hnb,
                  const float* __restrict__ Wself,
                  const float* __restrict__ Wneigh,
                  const float* __restrict__ bneigh,
                  const float* __restrict__ Wpred,
                  const float* __restrict__ bpred,
                  float* __restrict__ tout,
                  float* __restrict__ outp) {
    __shared__ __align__(16) char smem[47872];
    unsigned short* Asb = (unsigned short*)smem;            // [128][ASTR]
    unsigned short* Bsb = (unsigned short*)(smem + 10240);  // [128][BSTR]
    unsigned short* A2  = (unsigned short*)smem;            // [128][A2STR]
    unsigned short* WpT = (unsigned short*)(smem + 34816);  // [48][A2STR]

    int tid  = threadIdx.x;
    int lane = tid & 63;
    int w    = tid >> 6;
    int wm   = w >> 1;
    int wn   = w & 1;
    int lr   = lane & 15;
    int lq   = lane >> 4;
    int brow = blockIdx.x * TM;

    // Stage W_pred^T once (region never touched by phase 1).
    for (int i = tid; i < 48 * 128; i += 256) {
        int k = i & 127, col = i >> 7;
        WpT[col * A2STR + k] = (col < CLS) ? f2b(Wpred[k * CLS + col]) : (unsigned short)0;
    }

    f32x4 acc[4][4];
    #pragma unroll
    for (int i = 0; i < 4; ++i)
        #pragma unroll
        for (int j = 0; j < 4; ++j) acc[i][j] = (f32x4){0.f, 0.f, 0.f, 0.f};

    for (int k0 = 0; k0 < KTOT; k0 += 32) {
        if (BF16IN) {
            #pragma unroll
            for (int i = 0; i < 2; ++i) {
                int u = tid + 256 * i;    // 0..511
                int row = u >> 2;         // 0..127
                int c8 = u & 3;           // 8-bf16 group
                int node = brow + row;
                uint4 v = {0u, 0u, 0u, 0u};
                if (node < N_NODES) {
                    const unsigned short* sp = (k0 < FEAT)
                        ? featb + (size_t)node * FEAT + k0
                        : hnb   + (size_t)node * FEAT + (k0 - FEAT);
                    v = *reinterpret_cast<const uint4*>(sp + c8 * 8);
                }
                *reinterpret_cast<uint4*>(&Asb[row * ASTR + c8 * 8]) = v;
            }
        } else {
            #pragma unroll
            for (int i = 0; i < 4; ++i) {
                int u   = tid + 256 * i;  // 0..1023
                int row = u >> 3;
                int c4  = u & 7;
                int node = brow + row;
                int k = k0 + c4 * 4;
                float4 v = make_float4(0.f, 0.f, 0.f, 0.f);
                if (node < N_NODES) {
                    const float* base = (k < FEAT)
                        ? feat + (size_t)node * FEAT + k
                        : hn   + (size_t)node * FEAT + (k - FEAT);
                    v = *reinterpret_cast<const float4*>(base);
                }
                ushort4 p;
                p.x = f2b(v.x); p.y = f2b(v.y); p.z = f2b(v.z); p.w = f2b(v.w);
                *reinterpret_cast<ushort4*>(&Asb[row * ASTR + c4 * 4]) = p;
            }
        }
        // Stage B transposed (from f32 W, strided coalesced col reads).
        #pragma unroll
        for (int i = 0; i < 4; ++i) {
            int u  = tid + 256 * i;
            int n  = u & 127;
            int kq = u >> 7;              // 0..7
            int k  = k0 + kq * 4;
            const float* base = ((k < FEAT) ? (Wself + (size_t)k * FEAT)
                                            : (Wneigh + (size_t)(k - FEAT) * FEAT)) + n;
            ushort4 p;
            p.x = f2b(base[0]);
            p.y = f2b(base[FEAT]);
            p.z = f2b(base[2 * FEAT]);
            p.w = f2b(base[3 * FEAT]);
            *reinterpret_cast<ushort4*>(&Bsb[n * BSTR + kq * 4]) = p;
        }
        __syncthreads();

        short8 af[4], bfr[4];
        #pragma unroll
        for (int mi = 0; mi < 4; ++mi) {
            int row = wm * 64 + mi * 16 + lr;
            *reinterpret_cast<uint4*>(&af[mi]) =
                *reinterpret_cast<const uint4*>(&Asb[row * ASTR + lq * 8]);
        }
        #pragma unroll
        for (int ni = 0; ni < 4; ++ni) {
            int col = wn * 64 + ni * 16 + lr;
            const unsigned short* bp = &Bsb[col * BSTR + lq * 8];
            *reinterpret_cast<uint2*>(&bfr[ni]) = *reinterpret_cast<const uint2*>(bp);
            *(reinterpret_cast<uint2*>(&bfr[ni]) + 1) = *reinterpret_cast<const uint2*>(bp + 4);
        }
        #pragma unroll
        for (int mi = 0; mi < 4; ++mi)
            #pragma unroll
            for (int ni = 0; ni < 4; ++ni)
                acc[mi][ni] = __builtin_amdgcn_mfma_f32_16x16x32_bf16(
                    af[mi], bfr[ni], acc[mi][ni], 0, 0, 0);
        __syncthreads();
    }

    // Epilogue 1: bias + ReLU; store t; deposit bf16 t-tile into A2.
    #pragma unroll
    for (int ni = 0; ni < 4; ++ni) {
        int col = wn * 64 + ni * 16 + lr;
        float bn = bneigh[col];
        #pragma unroll
        for (int mi = 0; mi < 4; ++mi) {
            int rbase = wm * 64 + mi * 16 + lq * 4;
            #pragma unroll
            for (int r = 0; r < 4; ++r) {
                int lrow = rbase + r;
                float v = fmaxf(acc[mi][ni][r] + bn, 0.f);
                A2[lrow * A2STR + col] = f2b(v);
                int grow = brow + lrow;
                if (grow < N_NODES) tout[(size_t)grow * FEAT + col] = v;
            }
        }
    }
    __syncthreads();

    // Phase 2: out[128][40] = t_tile @ Wp + bp. wave w: rows [w*32, w*32+32).
    f32x4 oacc[2][3];
    #pragma unroll
    for (int i = 0; i < 2; ++i)
        #pragma unroll
        for (int j = 0; j < 3; ++j) oacc[i][j] = (f32x4){0.f, 0.f, 0.f, 0.f};

    #pragma unroll
    for (int ks = 0; ks < 4; ++ks) {
        short8 a2f[2], b2fr[3];
        #pragma unroll
        for (int rf = 0; rf < 2; ++rf) {
            int row = w * 32 + rf * 16 + lr;
            *reinterpret_cast<uint4*>(&a2f[rf]) =
                *reinterpret_cast<const uint4*>(&A2[row * A2STR + ks * 32 + lq * 8]);
        }
        #pragma unroll
        for (int cf = 0; cf < 3; ++cf) {
            int col = cf * 16 + lr;
            *reinterpret_cast<uint4*>(&b2fr[cf]) =
                *reinterpret_cast<const uint4*>(&WpT[col * A2STR + ks * 32 + lq * 8]);
        }
        #pragma unroll
        for (int rf = 0; rf < 2; ++rf)
            #pragma unroll
            for (int cf = 0; cf < 3; ++cf)
                oacc[rf][cf] = __builtin_amdgcn_mfma_f32_16x16x32_bf16(
                    a2f[rf], b2fr[cf], oacc[rf][cf], 0, 0, 0);
    }
    #pragma unroll
    for (int cf = 0; cf < 3; ++cf) {
        int col = cf * 16 + lr;
        if (col < CLS) {
            float bp = bpred[col];
            #pragma unroll
            for (int rf = 0; rf < 2; ++rf) {
                int rbase = brow + w * 32 + rf * 16 + lq * 4;
                #pragma unroll
                for (int r = 0; r < 4; ++r) {
                    int grow = rbase + r;
                    if (grow < N_NODES)
                        outp[(size_t)grow * CLS + col] = oacc[rf][cf][r] + bp;
                }
            }
        }
    }
}

extern "C" void kernel_launch(void* const* d_in, const int* in_sizes, int n_in,
                              void* d_out, int out_size, void* d_ws, size_t ws_size,
                              hipStream_t stream) {
    const float* feat   = (const float*)d_in[0];
    const int*   src    = (const int*)d_in[1];
    const int*   dst    = (const int*)d_in[2];
    const float* Wself  = (const float*)d_in[3];
    const float* Wneigh = (const float*)d_in[4];
    const float* bneigh = (const float*)d_in[5];
    const float* Wpred  = (const float*)d_in[6];
    const float* bpred  = (const float*)d_in[7];

    // d_out layout: [ out : 100000*40 f32 | t : 100000*128 f32 ]
    float* obuf = (float*)d_out;
    float* tbuf = obuf + (size_t)N_NODES * CLS;

    int* deg     = (int*)d_ws;
    int* bsum    = deg + N_NODES;
    int* boff    = bsum + 512;
    int* rowptr  = boff + 512;
    int* cursor  = rowptr + (N_NODES + 1);
    int* csr_src = cursor + N_NODES;
    size_t int_bytes = ((3 * (size_t)N_NODES + 1025 + N_EDGES) * 4 + 255) & ~(size_t)255;
    unsigned short* featb = (unsigned short*)((char*)d_ws + int_bytes);
    unsigned short* hnb   = featb + (size_t)N_NODES * FEAT;
    size_t need = int_bytes + 2 * (size_t)N_NODES * FEAT * 2;
    bool full = ws_size >= need;

    (void)hipMemsetAsync(deg, 0, N_NODES * sizeof(int), stream);

    deg_kernel<<<(N_EDGES + 255) / 256, 256, 0, stream>>>(dst, deg);
    bsum_kernel<<<NBLK, 256, 0, stream>>>(deg, bsum);
    bscan_kernel<<<1, 512, 0, stream>>>(bsum, boff);
    rowptr_kernel<<<NBLK, 256, 0, stream>>>(deg, boff, rowptr, cursor);
    fill_kernel<<<(N_EDGES + 255) / 256, 256, 0, stream>>>(src, dst, cursor, csr_src);

    if (full) {
        feat2bf_kernel<<<(N_NODES * FEAT / 8 + 255) / 256, 256, 0, stream>>>(feat, featb);
        hnb_kernel<<<(N_NODES + 3) / 4, 256, 0, stream>>>(featb, rowptr, csr_src, hnb);
        tgemm_kernel<1><<<(N_NODES + TM - 1) / TM, 256, 0, stream>>>(
            feat, nullptr, featb, hnb, Wself, Wneigh, bneigh, Wpred, bpred, tbuf, obuf);
    } else {
        float* hn = tbuf;  // gather into t-region, overwritten per-row by tgemm
        hn_kernel<<<(N_NODES + 3) / 4, 256, 0, stream>>>(feat, rowptr, csr_src, hn);
        tgemm_kernel<0><<<(N_NODES + TM - 1) / TM, 256, 0, stream>>>(
            feat, hn, nullptr, nullptr, Wself, Wneigh, bneigh, Wpred, bpred, tbuf, obuf);
    }
}

// Round 13
// 174.773 us; speedup vs baseline: 3.4413x; 1.1880x over previous
//
#include <hip/hip_runtime.h>
#include <hip/hip_bf16.h>

#define N_NODES 100000
#define N_EDGES 600000
#define FEAT 128
#define KTOT 256
#define CLS 40
#define TM 128
#define NBLK 391   // ceil(N_NODES/256)

typedef __attribute__((ext_vector_type(8))) short short8;
typedef __attribute__((ext_vector_type(4))) float f32x4;

__device__ __forceinline__ unsigned short f2b(float f) {
    __hip_bfloat16 h = __float2bfloat16(f);
    return *reinterpret_cast<unsigned short*>(&h);
}
__device__ __forceinline__ float b2f(unsigned int u16) {
    return __uint_as_float(u16 << 16);
}

// ---------- CSR build ----------
__global__ void deg_kernel(const int* __restrict__ dst, int* __restrict__ deg) {
    int e = blockIdx.x * 256 + threadIdx.x;
    if (e < N_EDGES) atomicAdd(&deg[dst[e]], 1);
}

__global__ void bsum_kernel(const int* __restrict__ deg, int* __restrict__ bsum) {
    __shared__ int s[256];
    int gi = blockIdx.x * 256 + threadIdx.x;
    s[threadIdx.x] = (gi < N_NODES) ? deg[gi] : 0;
    __syncthreads();
    for (int st = 128; st > 0; st >>= 1) {
        if (threadIdx.x < st) s[threadIdx.x] += s[threadIdx.x + st];
        __syncthreads();
    }
    if (threadIdx.x == 0) bsum[blockIdx.x] = s[0];
}

__global__ void bscan_kernel(const int* __restrict__ bsum, int* __restrict__ boff) {
    __shared__ int s[512];
    int t = threadIdx.x;
    int v = (t < NBLK) ? bsum[t] : 0;
    s[t] = v;
    __syncthreads();
    for (int st = 1; st < 512; st <<= 1) {
        int add = (t >= st) ? s[t - st] : 0;
        __syncthreads();
        s[t] += add;
        __syncthreads();
    }
    if (t < NBLK) boff[t] = s[t] - v;
}

__global__ void rowptr_kernel(const int* __restrict__ deg,
                              const int* __restrict__ boff,
                              int* __restrict__ rowptr,
                              int* __restrict__ cursor) {
    __shared__ int s[256];
    int t = threadIdx.x;
    int gi = blockIdx.x * 256 + t;
    int v = (gi < N_NODES) ? deg[gi] : 0;
    s[t] = v;
    __syncthreads();
    for (int st = 1; st < 256; st <<= 1) {
        int add = (t >= st) ? s[t - st] : 0;
        __syncthreads();
        s[t] += add;
        __syncthreads();
    }
    if (gi < N_NODES) {
        int excl = boff[blockIdx.x] + s[t] - v;
        rowptr[gi] = excl;
        cursor[gi] = excl;
        if (gi == N_NODES - 1) rowptr[N_NODES] = excl + v;
    }
}

__global__ void fill_kernel(const int* __restrict__ src, const int* __restrict__ dst,
                            int* __restrict__ cursor, int* __restrict__ csr_src) {
    int e = blockIdx.x * 256 + threadIdx.x;
    if (e >= N_EDGES) return;
    int pos = atomicAdd(&cursor[dst[e]], 1);
    csr_src[pos] = src[e];
}

// ---------- feat f32 -> bf16 ----------
__global__ __launch_bounds__(256, 8)
void feat2bf_kernel(const float* __restrict__ f, unsigned short* __restrict__ o) {
    size_t i = ((size_t)blockIdx.x * 256 + threadIdx.x) * 8;
    float4 a = *reinterpret_cast<const float4*>(f + i);
    float4 b = *reinterpret_cast<const float4*>(f + i + 4);
    ushort4 p0, p1;
    p0.x = f2b(a.x); p0.y = f2b(a.y); p0.z = f2b(a.z); p0.w = f2b(a.w);
    p1.x = f2b(b.x); p1.y = f2b(b.y); p1.z = f2b(b.z); p1.w = f2b(b.w);
    uint4 q;
    q.x = (unsigned)p0.x | ((unsigned)p0.y << 16);
    q.y = (unsigned)p0.z | ((unsigned)p0.w << 16);
    q.z = (unsigned)p1.x | ((unsigned)p1.y << 16);
    q.w = (unsigned)p1.z | ((unsigned)p1.w << 16);
    *reinterpret_cast<uint4*>(o + i) = q;
}

// ---------- h_neigh gather bf16: one wave/node, ILP-4 unrolled ----------
__global__ __launch_bounds__(256, 8)
void hnb_kernel(const unsigned short* __restrict__ featb,
                const int* __restrict__ rowptr,
                const int* __restrict__ csr_src,
                unsigned short* __restrict__ hnb) {
    int node = blockIdx.x * 4 + (threadIdx.x >> 6);
    int lane = threadIdx.x & 63;
    if (node >= N_NODES) return;
    int r0 = rowptr[node], r1 = rowptr[node + 1];
    float sx = 0.f, sy = 0.f;
    int p = r0;
    // chunks of 4: 4 independent idx loads, then 4 independent row loads in flight
    for (; p + 4 <= r1; p += 4) {
        int nb0 = csr_src[p + 0];
        int nb1 = csr_src[p + 1];
        int nb2 = csr_src[p + 2];
        int nb3 = csr_src[p + 3];
        unsigned int v0 = *reinterpret_cast<const unsigned int*>(featb + (size_t)nb0 * FEAT + lane * 2);
        unsigned int v1 = *reinterpret_cast<const unsigned int*>(featb + (size_t)nb1 * FEAT + lane * 2);
        unsigned int v2 = *reinterpret_cast<const unsigned int*>(featb + (size_t)nb2 * FEAT + lane * 2);
        unsigned int v3 = *reinterpret_cast<const unsigned int*>(featb + (size_t)nb3 * FEAT + lane * 2);
        sx += (b2f(v0 & 0xffffu) + b2f(v1 & 0xffffu)) + (b2f(v2 & 0xffffu) + b2f(v3 & 0xffffu));
        sy += (b2f(v0 >> 16) + b2f(v1 >> 16)) + (b2f(v2 >> 16) + b2f(v3 >> 16));
    }
    // tail 0..3 (up to 2 in flight)
    if (p + 2 <= r1) {
        int nb0 = csr_src[p + 0];
        int nb1 = csr_src[p + 1];
        unsigned int v0 = *reinterpret_cast<const unsigned int*>(featb + (size_t)nb0 * FEAT + lane * 2);
        unsigned int v1 = *reinterpret_cast<const unsigned int*>(featb + (size_t)nb1 * FEAT + lane * 2);
        sx += b2f(v0 & 0xffffu) + b2f(v1 & 0xffffu);
        sy += b2f(v0 >> 16) + b2f(v1 >> 16);
        p += 2;
    }
    if (p < r1) {
        int nb = csr_src[p];
        unsigned int v = *reinterpret_cast<const unsigned int*>(featb + (size_t)nb * FEAT + lane * 2);
        sx += b2f(v & 0xffffu);
        sy += b2f(v >> 16);
    }
    float inv = 1.0f / fmaxf((float)(r1 - r0), 1.0f);
    unsigned int o = (unsigned)f2b(sx * inv) | ((unsigned)f2b(sy * inv) << 16);
    *reinterpret_cast<unsigned int*>(hnb + (size_t)node * FEAT + lane * 2) = o;
}

// f32 fallback gather (small-ws tier)
__global__ __launch_bounds__(256, 4)
void hn_kernel(const float* __restrict__ feat,
               const int* __restrict__ rowptr,
               const int* __restrict__ csr_src,
               float* __restrict__ hn) {
    int node = blockIdx.x * 4 + (threadIdx.x >> 6);
    int lane = threadIdx.x & 63;
    if (node >= N_NODES) return;
    int r0 = rowptr[node], r1 = rowptr[node + 1];
    float sx = 0.f, sy = 0.f;
    for (int p = r0; p < r1; ++p) {
        int nb = csr_src[p];
        float2 f = *reinterpret_cast<const float2*>(feat + (size_t)nb * FEAT + lane * 2);
        sx += f.x; sy += f.y;
    }
    float inv = 1.0f / fmaxf((float)(r1 - r0), 1.0f);
    float2 o; o.x = sx * inv; o.y = sy * inv;
    *reinterpret_cast<float2*>(hn + (size_t)node * FEAT + lane * 2) = o;
}

// ---------- fused: t = relu([feat|hn]@[Ws;Wn]+bn);  out = t@Wp + bp ----------
#define ASTR 40
#define BSTR 36
#define A2STR 136
// smem (bytes): [0,10240) Asb | [10240,19456) Bsb | phase2: [0,34816) A2 | [34816,47872) WpT
template <int BF16IN>
__global__ __launch_bounds__(256, 2)
void tgemm_kernel(const float* __restrict__ feat,
                  const float* __restrict__ hn,
                  const unsigned short* __restrict__ featb,
                  const unsigned short* __restrict__ hnb,
                  const float* __restrict__ Wself,
                  const float* __restrict__ Wneigh,
                  const float* __restrict__ bneigh,
                  const float* __restrict__ Wpred,
                  const float* __restrict__ bpred,
                  float* __restrict__ tout,
                  float* __restrict__ outp) {
    __shared__ __align__(16) char smem[47872];
    unsigned short* Asb = (unsigned short*)smem;            // [128][ASTR]
    unsigned short* Bsb = (unsigned short*)(smem + 10240);  // [128][BSTR]
    unsigned short* A2  = (unsigned short*)smem;            // [128][A2STR]
    unsigned short* WpT = (unsigned short*)(smem + 34816);  // [48][A2STR]

    int tid  = threadIdx.x;
    int lane = tid & 63;
    int w    = tid >> 6;
    int wm   = w >> 1;
    int wn   = w & 1;
    int lr   = lane & 15;
    int lq   = lane >> 4;
    int brow = blockIdx.x * TM;

    // Stage W_pred^T once (region never touched by phase 1).
    for (int i = tid; i < 48 * 128; i += 256) {
        int k = i & 127, col = i >> 7;
        WpT[col * A2STR + k] = (col < CLS) ? f2b(Wpred[k * CLS + col]) : (unsigned short)0;
    }

    f32x4 acc[4][4];
    #pragma unroll
    for (int i = 0; i < 4; ++i)
        #pragma unroll
        for (int j = 0; j < 4; ++j) acc[i][j] = (f32x4){0.f, 0.f, 0.f, 0.f};

    for (int k0 = 0; k0 < KTOT; k0 += 32) {
        if (BF16IN) {
            #pragma unroll
            for (int i = 0; i < 2; ++i) {
                int u = tid + 256 * i;    // 0..511
                int row = u >> 2;         // 0..127
                int c8 = u & 3;           // 8-bf16 group
                int node = brow + row;
                uint4 v = {0u, 0u, 0u, 0u};
                if (node < N_NODES) {
                    const unsigned short* sp = (k0 < FEAT)
                        ? featb + (size_t)node * FEAT + k0
                        : hnb   + (size_t)node * FEAT + (k0 - FEAT);
                    v = *reinterpret_cast<const uint4*>(sp + c8 * 8);
                }
                *reinterpret_cast<uint4*>(&Asb[row * ASTR + c8 * 8]) = v;
            }
        } else {
            #pragma unroll
            for (int i = 0; i < 4; ++i) {
                int u   = tid + 256 * i;  // 0..1023
                int row = u >> 3;
                int c4  = u & 7;
                int node = brow + row;
                int k = k0 + c4 * 4;
                float4 v = make_float4(0.f, 0.f, 0.f, 0.f);
                if (node < N_NODES) {
                    const float* base = (k < FEAT)
                        ? feat + (size_t)node * FEAT + k
                        : hn   + (size_t)node * FEAT + (k - FEAT);
                    v = *reinterpret_cast<const float4*>(base);
                }
                ushort4 p;
                p.x = f2b(v.x); p.y = f2b(v.y); p.z = f2b(v.z); p.w = f2b(v.w);
                *reinterpret_cast<ushort4*>(&Asb[row * ASTR + c4 * 4]) = p;
            }
        }
        // Stage B transposed (from f32 W, strided coalesced col reads).
        #pragma unroll
        for (int i = 0; i < 4; ++i) {
            int u  = tid + 256 * i;
            int n  = u & 127;
            int kq = u >> 7;              // 0..7
            int k  = k0 + kq * 4;
            const float* base = ((k < FEAT) ? (Wself + (size_t)k * FEAT)
                                            : (Wneigh + (size_t)(k - FEAT) * FEAT)) + n;
            ushort4 p;
            p.x = f2b(base[0]);
            p.y = f2b(base[FEAT]);
            p.z = f2b(base[2 * FEAT]);
            p.w = f2b(base[3 * FEAT]);
            *reinterpret_cast<ushort4*>(&Bsb[n * BSTR + kq * 4]) = p;
        }
        __syncthreads();

        short8 af[4], bfr[4];
        #pragma unroll
        for (int mi = 0; mi < 4; ++mi) {
            int row = wm * 64 + mi * 16 + lr;
            *reinterpret_cast<uint4*>(&af[mi]) =
                *reinterpret_cast<const uint4*>(&Asb[row * ASTR + lq * 8]);
        }
        #pragma unroll
        for (int ni = 0; ni < 4; ++ni) {
            int col = wn * 64 + ni * 16 + lr;
            const unsigned short* bp = &Bsb[col * BSTR + lq * 8];
            *reinterpret_cast<uint2*>(&bfr[ni]) = *reinterpret_cast<const uint2*>(bp);
            *(reinterpret_cast<uint2*>(&bfr[ni]) + 1) = *reinterpret_cast<const uint2*>(bp + 4);
        }
        #pragma unroll
        for (int mi = 0; mi < 4; ++mi)
            #pragma unroll
            for (int ni = 0; ni < 4; ++ni)
                acc[mi][ni] = __builtin_amdgcn_mfma_f32_16x16x32_bf16(
                    af[mi], bfr[ni], acc[mi][ni], 0, 0, 0);
        __syncthreads();
    }

    // Epilogue 1: bias + ReLU; store t; deposit bf16 t-tile into A2.
    #pragma unroll
    for (int ni = 0; ni < 4; ++ni) {
        int col = wn * 64 + ni * 16 + lr;
        float bn = bneigh[col];
        #pragma unroll
        for (int mi = 0; mi < 4; ++mi) {
            int rbase = wm * 64 + mi * 16 + lq * 4;
            #pragma unroll
            for (int r = 0; r < 4; ++r) {
                int lrow = rbase + r;
                float v = fmaxf(acc[mi][ni][r] + bn, 0.f);
                A2[lrow * A2STR + col] = f2b(v);
                int grow = brow + lrow;
                if (grow < N_NODES) tout[(size_t)grow * FEAT + col] = v;
            }
        }
    }
    __syncthreads();

    // Phase 2: out[128][40] = t_tile @ Wp + bp. wave w: rows [w*32, w*32+32).
    f32x4 oacc[2][3];
    #pragma unroll
    for (int i = 0; i < 2; ++i)
        #pragma unroll
        for (int j = 0; j < 3; ++j) oacc[i][j] = (f32x4){0.f, 0.f, 0.f, 0.f};

    #pragma unroll
    for (int ks = 0; ks < 4; ++ks) {
        short8 a2f[2], b2fr[3];
        #pragma unroll
        for (int rf = 0; rf < 2; ++rf) {
            int row = w * 32 + rf * 16 + lr;
            *reinterpret_cast<uint4*>(&a2f[rf]) =
                *reinterpret_cast<const uint4*>(&A2[row * A2STR + ks * 32 + lq * 8]);
        }
        #pragma unroll
        for (int cf = 0; cf < 3; ++cf) {
            int col = cf * 16 + lr;
            *reinterpret_cast<uint4*>(&b2fr[cf]) =
                *reinterpret_cast<const uint4*>(&WpT[col * A2STR + ks * 32 + lq * 8]);
        }
        #pragma unroll
        for (int rf = 0; rf < 2; ++rf)
            #pragma unroll
            for (int cf = 0; cf < 3; ++cf)
                oacc[rf][cf] = __builtin_amdgcn_mfma_f32_16x16x32_bf16(
                    a2f[rf], b2fr[cf], oacc[rf][cf], 0, 0, 0);
    }
    #pragma unroll
    for (int cf = 0; cf < 3; ++cf) {
        int col = cf * 16 + lr;
        if (col < CLS) {
            float bp = bpred[col];
            #pragma unroll
            for (int rf = 0; rf < 2; ++rf) {
                int rbase = brow + w * 32 + rf * 16 + lq * 4;
                #pragma unroll
                for (int r = 0; r < 4; ++r) {
                    int grow = rbase + r;
                    if (grow < N_NODES)
                        outp[(size_t)grow * CLS + col] = oacc[rf][cf][r] + bp;
                }
            }
        }
    }
}

extern "C" void kernel_launch(void* const* d_in, const int* in_sizes, int n_in,
                              void* d_out, int out_size, void* d_ws, size_t ws_size,
                              hipStream_t stream) {
    const float* feat   = (const float*)d_in[0];
    const int*   src    = (const int*)d_in[1];
    const int*   dst    = (const int*)d_in[2];
    const float* Wself  = (const float*)d_in[3];
    const float* Wneigh = (const float*)d_in[4];
    const float* bneigh = (const float*)d_in[5];
    const float* Wpred  = (const float*)d_in[6];
    const float* bpred  = (const float*)d_in[7];

    // d_out layout: [ out : 100000*40 f32 | t : 100000*128 f32 ]
    float* obuf = (float*)d_out;
    float* tbuf = obuf + (size_t)N_NODES * CLS;

    int* deg     = (int*)d_ws;
    int* bsum    = deg + N_NODES;
    int* boff    = bsum + 512;
    int* rowptr  = boff + 512;
    int* cursor  = rowptr + (N_NODES + 1);
    int* csr_src = cursor + N_NODES;
    size_t int_bytes = ((3 * (size_t)N_NODES + 1025 + N_EDGES) * 4 + 255) & ~(size_t)255;
    unsigned short* featb = (unsigned short*)((char*)d_ws + int_bytes);
    unsigned short* hnb   = featb + (size_t)N_NODES * FEAT;
    size_t need = int_bytes + 2 * (size_t)N_NODES * FEAT * 2;
    bool full = ws_size >= need;

    (void)hipMemsetAsync(deg, 0, N_NODES * sizeof(int), stream);

    deg_kernel<<<(N_EDGES + 255) / 256, 256, 0, stream>>>(dst, deg);
    bsum_kernel<<<NBLK, 256, 0, stream>>>(deg, bsum);
    bscan_kernel<<<1, 512, 0, stream>>>(bsum, boff);
    rowptr_kernel<<<NBLK, 256, 0, stream>>>(deg, boff, rowptr, cursor);
    fill_kernel<<<(N_EDGES + 255) / 256, 256, 0, stream>>>(src, dst, cursor, csr_src);

    if (full) {
        feat2bf_kernel<<<(N_NODES * FEAT / 8 + 255) / 256, 256, 0, stream>>>(feat, featb);
        hnb_kernel<<<(N_NODES + 3) / 4, 256, 0, stream>>>(featb, rowptr, csr_src, hnb);
        tgemm_kernel<1><<<(N_NODES + TM - 1) / TM, 256, 0, stream>>>(
            feat, nullptr, featb, hnb, Wself, Wneigh, bneigh, Wpred, bpred, tbuf, obuf);
    } else {
        float* hn = tbuf;  // gather into t-region, overwritten per-row by tgemm
        hn_kernel<<<(N_NODES + 3) / 4, 256, 0, stream>>>(feat, rowptr, csr_src, hn);
        tgemm_kernel<0><<<(N_NODES + TM - 1) / TM, 256, 0, stream>>>(
            feat, hn, nullptr, nullptr, Wself, Wneigh, bneigh, Wpred, bpred, tbuf, obuf);
    }
}

// Round 14
// 159.241 us; speedup vs baseline: 3.7770x; 1.0975x over previous
//
#include <hip/hip_runtime.h>
#include <hip/hip_bf16.h>

#define N_NODES 100000
#define N_EDGES 600000
#define FEAT 128
#define KTOT 256
#define CLS 40
#define TM 128
#define NBLK 391   // ceil(N_NODES/256)

typedef __attribute__((ext_vector_type(8))) short short8;
typedef __attribute__((ext_vector_type(4))) float f32x4;

__device__ __forceinline__ unsigned short f2b(float f) {
    __hip_bfloat16 h = __float2bfloat16(f);
    return *reinterpret_cast<unsigned short*>(&h);
}
__device__ __forceinline__ float b2f(unsigned int u16) {
    return __uint_as_float(u16 << 16);
}

// ---------- CSR build ----------
__global__ void deg_kernel(const int* __restrict__ dst, int* __restrict__ deg) {
    int e = blockIdx.x * 256 + threadIdx.x;
    if (e < N_EDGES) atomicAdd(&deg[dst[e]], 1);
}

__global__ void bsum_kernel(const int* __restrict__ deg, int* __restrict__ bsum) {
    __shared__ int s[256];
    int gi = blockIdx.x * 256 + threadIdx.x;
    s[threadIdx.x] = (gi < N_NODES) ? deg[gi] : 0;
    __syncthreads();
    for (int st = 128; st > 0; st >>= 1) {
        if (threadIdx.x < st) s[threadIdx.x] += s[threadIdx.x + st];
        __syncthreads();
    }
    if (threadIdx.x == 0) bsum[blockIdx.x] = s[0];
}

__global__ void bscan_kernel(const int* __restrict__ bsum, int* __restrict__ boff) {
    __shared__ int s[512];
    int t = threadIdx.x;
    int v = (t < NBLK) ? bsum[t] : 0;
    s[t] = v;
    __syncthreads();
    for (int st = 1; st < 512; st <<= 1) {
        int add = (t >= st) ? s[t - st] : 0;
        __syncthreads();
        s[t] += add;
        __syncthreads();
    }
    if (t < NBLK) boff[t] = s[t] - v;
}

__global__ void rowptr_kernel(const int* __restrict__ deg,
                              const int* __restrict__ boff,
                              int* __restrict__ rowptr,
                              int* __restrict__ cursor) {
    __shared__ int s[256];
    int t = threadIdx.x;
    int gi = blockIdx.x * 256 + t;
    int v = (gi < N_NODES) ? deg[gi] : 0;
    s[t] = v;
    __syncthreads();
    for (int st = 1; st < 256; st <<= 1) {
        int add = (t >= st) ? s[t - st] : 0;
        __syncthreads();
        s[t] += add;
        __syncthreads();
    }
    if (gi < N_NODES) {
        int excl = boff[blockIdx.x] + s[t] - v;
        rowptr[gi] = excl;
        cursor[gi] = excl;
        if (gi == N_NODES - 1) rowptr[N_NODES] = excl + v;
    }
}

__global__ void fill_kernel(const int* __restrict__ src, const int* __restrict__ dst,
                            int* __restrict__ cursor, int* __restrict__ csr_src) {
    int e = blockIdx.x * 256 + threadIdx.x;
    if (e >= N_EDGES) return;
    int pos = atomicAdd(&cursor[dst[e]], 1);
    csr_src[pos] = src[e];
}

// ---------- feat f32 -> bf16 ----------
__global__ __launch_bounds__(256, 8)
void feat2bf_kernel(const float* __restrict__ f, unsigned short* __restrict__ o) {
    size_t i = ((size_t)blockIdx.x * 256 + threadIdx.x) * 8;
    float4 a = *reinterpret_cast<const float4*>(f + i);
    float4 b = *reinterpret_cast<const float4*>(f + i + 4);
    ushort4 p0, p1;
    p0.x = f2b(a.x); p0.y = f2b(a.y); p0.z = f2b(a.z); p0.w = f2b(a.w);
    p1.x = f2b(b.x); p1.y = f2b(b.y); p1.z = f2b(b.z); p1.w = f2b(b.w);
    uint4 q;
    q.x = (unsigned)p0.x | ((unsigned)p0.y << 16);
    q.y = (unsigned)p0.z | ((unsigned)p0.w << 16);
    q.z = (unsigned)p1.x | ((unsigned)p1.y << 16);
    q.w = (unsigned)p1.z | ((unsigned)p1.w << 16);
    *reinterpret_cast<uint4*>(o + i) = q;
}

// ---------- h_neigh gather bf16: one wave/node, ILP-4 ----------
__global__ __launch_bounds__(256, 8)
void hnb_kernel(const unsigned short* __restrict__ featb,
                const int* __restrict__ rowptr,
                const int* __restrict__ csr_src,
                unsigned short* __restrict__ hnb) {
    int node = blockIdx.x * 4 + (threadIdx.x >> 6);
    int lane = threadIdx.x & 63;
    if (node >= N_NODES) return;
    int r0 = rowptr[node], r1 = rowptr[node + 1];
    float sx = 0.f, sy = 0.f;
    int p = r0;
    for (; p + 4 <= r1; p += 4) {
        int nb0 = csr_src[p + 0];
        int nb1 = csr_src[p + 1];
        int nb2 = csr_src[p + 2];
        int nb3 = csr_src[p + 3];
        unsigned int v0 = *reinterpret_cast<const unsigned int*>(featb + (size_t)nb0 * FEAT + lane * 2);
        unsigned int v1 = *reinterpret_cast<const unsigned int*>(featb + (size_t)nb1 * FEAT + lane * 2);
        unsigned int v2 = *reinterpret_cast<const unsigned int*>(featb + (size_t)nb2 * FEAT + lane * 2);
        unsigned int v3 = *reinterpret_cast<const unsigned int*>(featb + (size_t)nb3 * FEAT + lane * 2);
        sx += (b2f(v0 & 0xffffu) + b2f(v1 & 0xffffu)) + (b2f(v2 & 0xffffu) + b2f(v3 & 0xffffu));
        sy += (b2f(v0 >> 16) + b2f(v1 >> 16)) + (b2f(v2 >> 16) + b2f(v3 >> 16));
    }
    if (p + 2 <= r1) {
        int nb0 = csr_src[p + 0];
        int nb1 = csr_src[p + 1];
        unsigned int v0 = *reinterpret_cast<const unsigned int*>(featb + (size_t)nb0 * FEAT + lane * 2);
        unsigned int v1 = *reinterpret_cast<const unsigned int*>(featb + (size_t)nb1 * FEAT + lane * 2);
        sx += b2f(v0 & 0xffffu) + b2f(v1 & 0xffffu);
        sy += b2f(v0 >> 16) + b2f(v1 >> 16);
        p += 2;
    }
    if (p < r1) {
        int nb = csr_src[p];
        unsigned int v = *reinterpret_cast<const unsigned int*>(featb + (size_t)nb * FEAT + lane * 2);
        sx += b2f(v & 0xffffu);
        sy += b2f(v >> 16);
    }
    float inv = 1.0f / fmaxf((float)(r1 - r0), 1.0f);
    unsigned int o = (unsigned)f2b(sx * inv) | ((unsigned)f2b(sy * inv) << 16);
    *reinterpret_cast<unsigned int*>(hnb + (size_t)node * FEAT + lane * 2) = o;
}

// f32 fallback gather (small-ws tier)
__global__ __launch_bounds__(256, 4)
void hn_kernel(const float* __restrict__ feat,
               const int* __restrict__ rowptr,
               const int* __restrict__ csr_src,
               float* __restrict__ hn) {
    int node = blockIdx.x * 4 + (threadIdx.x >> 6);
    int lane = threadIdx.x & 63;
    if (node >= N_NODES) return;
    int r0 = rowptr[node], r1 = rowptr[node + 1];
    float sx = 0.f, sy = 0.f;
    for (int p = r0; p < r1; ++p) {
        int nb = csr_src[p];
        float2 f = *reinterpret_cast<const float2*>(feat + (size_t)nb * FEAT + lane * 2);
        sx += f.x; sy += f.y;
    }
    float inv = 1.0f / fmaxf((float)(r1 - r0), 1.0f);
    float2 o; o.x = sx * inv; o.y = sy * inv;
    *reinterpret_cast<float2*>(hn + (size_t)node * FEAT + lane * 2) = o;
}

// ---------- fused: t = relu([feat|hn]@[Ws;Wn]+bn);  out = t@Wp + bp ----------
// Phase 1: 128x128 MFMA tile. Phase 2: two 64-row halves vs WpT.
// LDS (bytes): Asb [0,10240) | Bsb [10240,19456) | A2h [0,19456) | WpT [19456,34048)
#define ASTR 40
#define BSTR 36
#define A2HSTR 152
template <int BF16IN>
__global__ __launch_bounds__(256, 4)
void tgemm_kernel(const float* __restrict__ feat,
                  const float* __restrict__ hn,
                  const unsigned short* __restrict__ featb,
                  const unsigned short* __restrict__ hnb,
                  const float* __restrict__ Wself,
                  const float* __restrict__ Wneigh,
                  const float* __restrict__ bneigh,
                  const float* __restrict__ Wpred,
                  const float* __restrict__ bpred,
                  float* __restrict__ tout,
                  float* __restrict__ outp) {
    __shared__ __align__(16) char smem[34048];
    unsigned short* Asb = (unsigned short*)smem;            // [128][ASTR]
    unsigned short* Bsb = (unsigned short*)(smem + 10240);  // [128][BSTR]
    unsigned short* A2h = (unsigned short*)smem;            // [64][A2HSTR]
    unsigned short* WpT = (unsigned short*)(smem + 19456);  // [48][A2HSTR]

    int tid  = threadIdx.x;
    int lane = tid & 63;
    int w    = tid >> 6;
    int wm   = w >> 1;
    int wn   = w & 1;
    int lr   = lane & 15;
    int lq   = lane >> 4;
    int brow = blockIdx.x * TM;

    // Stage W_pred^T (region disjoint from phase-1 buffers; persists).
    for (int i = tid; i < FEAT * CLS; i += 256) {   // coalesced read of Wpred
        int k = i / CLS, col = i - k * CLS;
        WpT[col * A2HSTR + k] = f2b(Wpred[i]);
    }
    for (int i = tid; i < 8 * FEAT; i += 256) {     // zero-fill cols 40..47
        int k = i & 127, col = CLS + (i >> 7);
        WpT[col * A2HSTR + k] = 0;
    }

    f32x4 acc[4][4];
    #pragma unroll
    for (int i = 0; i < 4; ++i)
        #pragma unroll
        for (int j = 0; j < 4; ++j) acc[i][j] = (f32x4){0.f, 0.f, 0.f, 0.f};

    for (int k0 = 0; k0 < KTOT; k0 += 32) {
        if (BF16IN) {
            #pragma unroll
            for (int i = 0; i < 2; ++i) {
                int u = tid + 256 * i;    // 0..511
                int row = u >> 2;
                int c8 = u & 3;
                int node = brow + row;
                uint4 v = {0u, 0u, 0u, 0u};
                if (node < N_NODES) {
                    const unsigned short* sp = (k0 < FEAT)
                        ? featb + (size_t)node * FEAT + k0
                        : hnb   + (size_t)node * FEAT + (k0 - FEAT);
                    v = *reinterpret_cast<const uint4*>(sp + c8 * 8);
                }
                *reinterpret_cast<uint4*>(&Asb[row * ASTR + c8 * 8]) = v;
            }
        } else {
            #pragma unroll
            for (int i = 0; i < 4; ++i) {
                int u   = tid + 256 * i;
                int row = u >> 3;
                int c4  = u & 7;
                int node = brow + row;
                int k = k0 + c4 * 4;
                float4 v = make_float4(0.f, 0.f, 0.f, 0.f);
                if (node < N_NODES) {
                    const float* base = (k < FEAT)
                        ? feat + (size_t)node * FEAT + k
                        : hn   + (size_t)node * FEAT + (k - FEAT);
                    v = *reinterpret_cast<const float4*>(base);
                }
                ushort4 p;
                p.x = f2b(v.x); p.y = f2b(v.y); p.z = f2b(v.z); p.w = f2b(v.w);
                *reinterpret_cast<ushort4*>(&Asb[row * ASTR + c4 * 4]) = p;
            }
        }
        #pragma unroll
        for (int i = 0; i < 4; ++i) {
            int u  = tid + 256 * i;
            int n  = u & 127;
            int kq = u >> 7;
            int k  = k0 + kq * 4;
            const float* base = ((k < FEAT) ? (Wself + (size_t)k * FEAT)
                                            : (Wneigh + (size_t)(k - FEAT) * FEAT)) + n;
            ushort4 p;
            p.x = f2b(base[0]);
            p.y = f2b(base[FEAT]);
            p.z = f2b(base[2 * FEAT]);
            p.w = f2b(base[3 * FEAT]);
            *reinterpret_cast<ushort4*>(&Bsb[n * BSTR + kq * 4]) = p;
        }
        __syncthreads();

        short8 af[4], bfr[4];
        #pragma unroll
        for (int mi = 0; mi < 4; ++mi) {
            int row = wm * 64 + mi * 16 + lr;
            *reinterpret_cast<uint4*>(&af[mi]) =
                *reinterpret_cast<const uint4*>(&Asb[row * ASTR + lq * 8]);
        }
        #pragma unroll
        for (int ni = 0; ni < 4; ++ni) {
            int col = wn * 64 + ni * 16 + lr;
            const unsigned short* bp = &Bsb[col * BSTR + lq * 8];
            *reinterpret_cast<uint2*>(&bfr[ni]) = *reinterpret_cast<const uint2*>(bp);
            *(reinterpret_cast<uint2*>(&bfr[ni]) + 1) = *reinterpret_cast<const uint2*>(bp + 4);
        }
        #pragma unroll
        for (int mi = 0; mi < 4; ++mi)
            #pragma unroll
            for (int ni = 0; ni < 4; ++ni)
                acc[mi][ni] = __builtin_amdgcn_mfma_f32_16x16x32_bf16(
                    af[mi], bfr[ni], acc[mi][ni], 0, 0, 0);
        __syncthreads();
    }

    // Epilogue: bias+ReLU folded into acc; store t.
    #pragma unroll
    for (int ni = 0; ni < 4; ++ni) {
        int col = wn * 64 + ni * 16 + lr;
        float bn = bneigh[col];
        #pragma unroll
        for (int mi = 0; mi < 4; ++mi) {
            #pragma unroll
            for (int r = 0; r < 4; ++r) {
                float v = fmaxf(acc[mi][ni][r] + bn, 0.f);
                acc[mi][ni][r] = v;
                int grow = brow + wm * 64 + mi * 16 + lq * 4 + r;
                if (grow < N_NODES) tout[(size_t)grow * FEAT + col] = v;
            }
        }
    }

    // Phase 2, two halves of 64 rows each.
    #pragma unroll
    for (int h = 0; h < 2; ++h) {
        if (wm == h) {   // deposit this half's t-tile (rows h*64..h*64+63)
            #pragma unroll
            for (int ni = 0; ni < 4; ++ni) {
                int col = wn * 64 + ni * 16 + lr;
                #pragma unroll
                for (int mi = 0; mi < 4; ++mi)
                    #pragma unroll
                    for (int r = 0; r < 4; ++r)
                        A2h[(mi * 16 + lq * 4 + r) * A2HSTR + col] = f2b(acc[mi][ni][r]);
            }
        }
        __syncthreads();
        // all 4 waves compute: wave w -> rows h*64 + w*16 .. +16
        f32x4 oacc[3];
        #pragma unroll
        for (int j = 0; j < 3; ++j) oacc[j] = (f32x4){0.f, 0.f, 0.f, 0.f};
        #pragma unroll
        for (int ks = 0; ks < 4; ++ks) {
            short8 a2f, b2fr[3];
            *reinterpret_cast<uint4*>(&a2f) =
                *reinterpret_cast<const uint4*>(&A2h[(w * 16 + lr) * A2HSTR + ks * 32 + lq * 8]);
            #pragma unroll
            for (int cf = 0; cf < 3; ++cf)
                *reinterpret_cast<uint4*>(&b2fr[cf]) =
                    *reinterpret_cast<const uint4*>(&WpT[(cf * 16 + lr) * A2HSTR + ks * 32 + lq * 8]);
            #pragma unroll
            for (int cf = 0; cf < 3; ++cf)
                oacc[cf] = __builtin_amdgcn_mfma_f32_16x16x32_bf16(a2f, b2fr[cf], oacc[cf], 0, 0, 0);
        }
        #pragma unroll
        for (int cf = 0; cf < 3; ++cf) {
            int col = cf * 16 + lr;
            if (col < CLS) {
                float bp = bpred[col];
                #pragma unroll
                for (int r = 0; r < 4; ++r) {
                    int grow = brow + h * 64 + w * 16 + lq * 4 + r;
                    if (grow < N_NODES)
                        outp[(size_t)grow * CLS + col] = oacc[cf][r] + bp;
                }
            }
        }
        __syncthreads();
    }
}

extern "C" void kernel_launch(void* const* d_in, const int* in_sizes, int n_in,
                              void* d_out, int out_size, void* d_ws, size_t ws_size,
                              hipStream_t stream) {
    const float* feat   = (const float*)d_in[0];
    const int*   src    = (const int*)d_in[1];
    const int*   dst    = (const int*)d_in[2];
    const float* Wself  = (const float*)d_in[3];
    const float* Wneigh = (const float*)d_in[4];
    const float* bneigh = (const float*)d_in[5];
    const float* Wpred  = (const float*)d_in[6];
    const float* bpred  = (const float*)d_in[7];

    // d_out layout: [ out : 100000*40 f32 | t : 100000*128 f32 ]
    float* obuf = (float*)d_out;
    float* tbuf = obuf + (size_t)N_NODES * CLS;

    int* deg     = (int*)d_ws;
    int* bsum    = deg + N_NODES;
    int* boff    = bsum + 512;
    int* rowptr  = boff + 512;
    int* cursor  = rowptr + (N_NODES + 1);
    int* csr_src = cursor + N_NODES;
    size_t int_bytes = ((3 * (size_t)N_NODES + 1025 + N_EDGES) * 4 + 255) & ~(size_t)255;
    unsigned short* featb = (unsigned short*)((char*)d_ws + int_bytes);
    unsigned short* hnb   = featb + (size_t)N_NODES * FEAT;
    size_t need = int_bytes + 2 * (size_t)N_NODES * FEAT * 2;
    bool full = ws_size >= need;

    (void)hipMemsetAsync(deg, 0, N_NODES * sizeof(int), stream);

    deg_kernel<<<(N_EDGES + 255) / 256, 256, 0, stream>>>(dst, deg);
    bsum_kernel<<<NBLK, 256, 0, stream>>>(deg, bsum);
    bscan_kernel<<<1, 512, 0, stream>>>(bsum, boff);
    rowptr_kernel<<<NBLK, 256, 0, stream>>>(deg, boff, rowptr, cursor);
    fill_kernel<<<(N_EDGES + 255) / 256, 256, 0, stream>>>(src, dst, cursor, csr_src);

    if (full) {
        feat2bf_kernel<<<(N_NODES * FEAT / 8 + 255) / 256, 256, 0, stream>>>(feat, featb);
        hnb_kernel<<<(N_NODES + 3) / 4, 256, 0, stream>>>(featb, rowptr, csr_src, hnb);
        tgemm_kernel<1><<<(N_NODES + TM - 1) / TM, 256, 0, stream>>>(
            feat, nullptr, featb, hnb, Wself, Wneigh, bneigh, Wpred, bpred, tbuf, obuf);
    } else {
        float* hn = tbuf;
        hn_kernel<<<(N_NODES + 3) / 4, 256, 0, stream>>>(feat, rowptr, csr_src, hn);
        tgemm_kernel<0><<<(N_NODES + TM - 1) / TM, 256, 0, stream>>>(
            feat, hn, nullptr, nullptr, Wself, Wneigh, bneigh, Wpred, bpred, tbuf, obuf);
    }
}

// Round 15
// 154.693 us; speedup vs baseline: 3.8880x; 1.0294x over previous
//
#include <hip/hip_runtime.h>
#include <hip/hip_bf16.h>

#define N_NODES 100000
#define N_EDGES 600000
#define FEAT 128
#define KTOT 256
#define CLS 40
#define TM 64
#define NB2 1563   // ceil(N_NODES/TM)
#define NBLK 391   // ceil(N_NODES/256)

typedef __attribute__((ext_vector_type(8))) short short8;
typedef __attribute__((ext_vector_type(4))) float f32x4;

__device__ __forceinline__ unsigned short f2b(float f) {
    __hip_bfloat16 h = __float2bfloat16(f);
    return *reinterpret_cast<unsigned short*>(&h);
}
__device__ __forceinline__ float b2f(unsigned int u16) {
    return __uint_as_float(u16 << 16);
}

// ---------- CSR build ----------
__global__ void deg_kernel(const int* __restrict__ dst, int* __restrict__ deg) {
    int e = blockIdx.x * 256 + threadIdx.x;
    if (e < N_EDGES) atomicAdd(&deg[dst[e]], 1);
}

__global__ void bsum_kernel(const int* __restrict__ deg, int* __restrict__ bsum) {
    __shared__ int s[256];
    int gi = blockIdx.x * 256 + threadIdx.x;
    s[threadIdx.x] = (gi < N_NODES) ? deg[gi] : 0;
    __syncthreads();
    for (int st = 128; st > 0; st >>= 1) {
        if (threadIdx.x < st) s[threadIdx.x] += s[threadIdx.x + st];
        __syncthreads();
    }
    if (threadIdx.x == 0) bsum[blockIdx.x] = s[0];
}

__global__ void bscan_kernel(const int* __restrict__ bsum, int* __restrict__ boff) {
    __shared__ int s[512];
    int t = threadIdx.x;
    int v = (t < NBLK) ? bsum[t] : 0;
    s[t] = v;
    __syncthreads();
    for (int st = 1; st < 512; st <<= 1) {
        int add = (t >= st) ? s[t - st] : 0;
        __syncthreads();
        s[t] += add;
        __syncthreads();
    }
    if (t < NBLK) boff[t] = s[t] - v;
}

__global__ void rowptr_kernel(const int* __restrict__ deg,
                              const int* __restrict__ boff,
                              int* __restrict__ rowptr,
                              int* __restrict__ cursor) {
    __shared__ int s[256];
    int t = threadIdx.x;
    int gi = blockIdx.x * 256 + t;
    int v = (gi < N_NODES) ? deg[gi] : 0;
    s[t] = v;
    __syncthreads();
    for (int st = 1; st < 256; st <<= 1) {
        int add = (t >= st) ? s[t - st] : 0;
        __syncthreads();
        s[t] += add;
        __syncthreads();
    }
    if (gi < N_NODES) {
        int excl = boff[blockIdx.x] + s[t] - v;
        rowptr[gi] = excl;
        cursor[gi] = excl;
        if (gi == N_NODES - 1) rowptr[N_NODES] = excl + v;
    }
}

__global__ void fill_kernel(const int* __restrict__ src, const int* __restrict__ dst,
                            int* __restrict__ cursor, int* __restrict__ csr_src) {
    int e = blockIdx.x * 256 + threadIdx.x;
    if (e >= N_EDGES) return;
    int pos = atomicAdd(&cursor[dst[e]], 1);
    csr_src[pos] = src[e];
}

// ---------- feat f32 -> bf16 ----------
__global__ __launch_bounds__(256, 8)
void feat2bf_kernel(const float* __restrict__ f, unsigned short* __restrict__ o) {
    size_t i = ((size_t)blockIdx.x * 256 + threadIdx.x) * 8;
    float4 a = *reinterpret_cast<const float4*>(f + i);
    float4 b = *reinterpret_cast<const float4*>(f + i + 4);
    ushort4 p0, p1;
    p0.x = f2b(a.x); p0.y = f2b(a.y); p0.z = f2b(a.z); p0.w = f2b(a.w);
    p1.x = f2b(b.x); p1.y = f2b(b.y); p1.z = f2b(b.z); p1.w = f2b(b.w);
    uint4 q;
    q.x = (unsigned)p0.x | ((unsigned)p0.y << 16);
    q.y = (unsigned)p0.z | ((unsigned)p0.w << 16);
    q.z = (unsigned)p1.x | ((unsigned)p1.y << 16);
    q.w = (unsigned)p1.z | ((unsigned)p1.w << 16);
    *reinterpret_cast<uint4*>(o + i) = q;
}

// ---------- h_neigh gather bf16: one wave/node, ILP-4 ----------
__global__ __launch_bounds__(256, 8)
void hnb_kernel(const unsigned short* __restrict__ featb,
                const int* __restrict__ rowptr,
                const int* __restrict__ csr_src,
                unsigned short* __restrict__ hnb) {
    int node = blockIdx.x * 4 + (threadIdx.x >> 6);
    int lane = threadIdx.x & 63;
    if (node >= N_NODES) return;
    int r0 = rowptr[node], r1 = rowptr[node + 1];
    float sx = 0.f, sy = 0.f;
    int p = r0;
    for (; p + 4 <= r1; p += 4) {
        int nb0 = csr_src[p + 0];
        int nb1 = csr_src[p + 1];
        int nb2 = csr_src[p + 2];
        int nb3 = csr_src[p + 3];
        unsigned int v0 = *reinterpret_cast<const unsigned int*>(featb + (size_t)nb0 * FEAT + lane * 2);
        unsigned int v1 = *reinterpret_cast<const unsigned int*>(featb + (size_t)nb1 * FEAT + lane * 2);
        unsigned int v2 = *reinterpret_cast<const unsigned int*>(featb + (size_t)nb2 * FEAT + lane * 2);
        unsigned int v3 = *reinterpret_cast<const unsigned int*>(featb + (size_t)nb3 * FEAT + lane * 2);
        sx += (b2f(v0 & 0xffffu) + b2f(v1 & 0xffffu)) + (b2f(v2 & 0xffffu) + b2f(v3 & 0xffffu));
        sy += (b2f(v0 >> 16) + b2f(v1 >> 16)) + (b2f(v2 >> 16) + b2f(v3 >> 16));
    }
    if (p + 2 <= r1) {
        int nb0 = csr_src[p + 0];
        int nb1 = csr_src[p + 1];
        unsigned int v0 = *reinterpret_cast<const unsigned int*>(featb + (size_t)nb0 * FEAT + lane * 2);
        unsigned int v1 = *reinterpret_cast<const unsigned int*>(featb + (size_t)nb1 * FEAT + lane * 2);
        sx += b2f(v0 & 0xffffu) + b2f(v1 & 0xffffu);
        sy += b2f(v0 >> 16) + b2f(v1 >> 16);
        p += 2;
    }
    if (p < r1) {
        int nb = csr_src[p];
        unsigned int v = *reinterpret_cast<const unsigned int*>(featb + (size_t)nb * FEAT + lane * 2);
        sx += b2f(v & 0xffffu);
        sy += b2f(v >> 16);
    }
    float inv = 1.0f / fmaxf((float)(r1 - r0), 1.0f);
    unsigned int o = (unsigned)f2b(sx * inv) | ((unsigned)f2b(sy * inv) << 16);
    *reinterpret_cast<unsigned int*>(hnb + (size_t)node * FEAT + lane * 2) = o;
}

// f32 fallback gather (small-ws tier)
__global__ __launch_bounds__(256, 4)
void hn_kernel(const float* __restrict__ feat,
               const int* __restrict__ rowptr,
               const int* __restrict__ csr_src,
               float* __restrict__ hn) {
    int node = blockIdx.x * 4 + (threadIdx.x >> 6);
    int lane = threadIdx.x & 63;
    if (node >= N_NODES) return;
    int r0 = rowptr[node], r1 = rowptr[node + 1];
    float sx = 0.f, sy = 0.f;
    for (int p = r0; p < r1; ++p) {
        int nb = csr_src[p];
        float2 f = *reinterpret_cast<const float2*>(feat + (size_t)nb * FEAT + lane * 2);
        sx += f.x; sy += f.y;
    }
    float inv = 1.0f / fmaxf((float)(r1 - r0), 1.0f);
    float2 o; o.x = sx * inv; o.y = sy * inv;
    *reinterpret_cast<float2*>(hn + (size_t)node * FEAT + lane * 2) = o;
}

// ---------- fused: t = relu([feat|hn]@[Ws;Wn]+bn);  out = t@Wp + bp ----------
// 64x128 tile, BK=64 (4 K-steps), 4 waves each 64x32.
// LDS: Asb [0,9216) | Bsb [9216,26624) || phase2: A2h [0,19456) | WpT [19456,34048)
#define ASTR 72
#define BSTR 68
#define A2HSTR 152
template <int BF16IN>
__global__ __launch_bounds__(256, 4)
void tgemm_kernel(const float* __restrict__ feat,
                  const float* __restrict__ hn,
                  const unsigned short* __restrict__ featb,
                  const unsigned short* __restrict__ hnb,
                  const float* __restrict__ Wself,
                  const float* __restrict__ Wneigh,
                  const float* __restrict__ bneigh,
                  const float* __restrict__ Wpred,
                  const float* __restrict__ bpred,
                  float* __restrict__ tout,
                  float* __restrict__ outp) {
    __shared__ __align__(16) char smem[34048];
    unsigned short* Asb = (unsigned short*)smem;            // [64][ASTR]
    unsigned short* Bsb = (unsigned short*)(smem + 9216);   // [128][BSTR]
    unsigned short* A2h = (unsigned short*)smem;            // [64][A2HSTR]
    unsigned short* WpT = (unsigned short*)(smem + 19456);  // [48][A2HSTR]

    int tid  = threadIdx.x;
    int lane = tid & 63;
    int w    = tid >> 6;        // wave 0..3 -> cols [w*32, w*32+32)
    int lr   = lane & 15;
    int lq   = lane >> 4;
    int brow = blockIdx.x * TM;

    f32x4 acc[4][2];
    #pragma unroll
    for (int i = 0; i < 4; ++i)
        #pragma unroll
        for (int j = 0; j < 2; ++j) acc[i][j] = (f32x4){0.f, 0.f, 0.f, 0.f};

    for (int k0 = 0; k0 < KTOT; k0 += 64) {
        // ---- Stage A: 64 rows x 64 k ----
        if (BF16IN) {
            #pragma unroll
            for (int i = 0; i < 2; ++i) {
                int u = tid + 256 * i;      // 0..511
                int row = u >> 3;           // 0..63
                int c8 = u & 7;             // 8-bf16 group
                int node = brow + row;
                uint4 v = {0u, 0u, 0u, 0u};
                if (node < N_NODES) {
                    const unsigned short* sp = (k0 < FEAT)
                        ? featb + (size_t)node * FEAT + k0
                        : hnb   + (size_t)node * FEAT + (k0 - FEAT);
                    v = *reinterpret_cast<const uint4*>(sp + c8 * 8);
                }
                *reinterpret_cast<uint4*>(&Asb[row * ASTR + c8 * 8]) = v;
            }
        } else {
            #pragma unroll
            for (int i = 0; i < 4; ++i) {
                int u   = tid + 256 * i;    // 0..1023
                int row = u >> 4;           // 0..63
                int c4  = u & 15;
                int node = brow + row;
                int k = k0 + c4 * 4;
                float4 v = make_float4(0.f, 0.f, 0.f, 0.f);
                if (node < N_NODES) {
                    const float* base = (k < FEAT)
                        ? feat + (size_t)node * FEAT + k
                        : hn   + (size_t)node * FEAT + (k - FEAT);
                    v = *reinterpret_cast<const float4*>(base);
                }
                ushort4 p;
                p.x = f2b(v.x); p.y = f2b(v.y); p.z = f2b(v.z); p.w = f2b(v.w);
                *reinterpret_cast<ushort4*>(&Asb[row * ASTR + c4 * 4]) = p;
            }
        }
        // ---- Stage B transposed: 128 cols x 64 k from f32 W ----
        #pragma unroll
        for (int i = 0; i < 8; ++i) {
            int u  = tid + 256 * i;         // 0..2047
            int n  = u & 127;
            int kq = u >> 7;                // 0..15
            int k  = k0 + kq * 4;
            const float* base = ((k0 < FEAT) ? (Wself + (size_t)k * FEAT)
                                             : (Wneigh + (size_t)(k - FEAT) * FEAT)) + n;
            ushort4 p;
            p.x = f2b(base[0]);
            p.y = f2b(base[FEAT]);
            p.z = f2b(base[2 * FEAT]);
            p.w = f2b(base[3 * FEAT]);
            *reinterpret_cast<ushort4*>(&Bsb[n * BSTR + kq * 4]) = p;
        }
        __syncthreads();

        #pragma unroll
        for (int ks = 0; ks < 2; ++ks) {
            short8 af[4], bfr[2];
            #pragma unroll
            for (int mi = 0; mi < 4; ++mi) {
                int row = mi * 16 + lr;
                *reinterpret_cast<uint4*>(&af[mi]) =
                    *reinterpret_cast<const uint4*>(&Asb[row * ASTR + ks * 32 + lq * 8]);
            }
            #pragma unroll
            for (int ni = 0; ni < 2; ++ni) {
                int col = w * 32 + ni * 16 + lr;
                const unsigned short* bp = &Bsb[col * BSTR + ks * 32 + lq * 8];
                *reinterpret_cast<uint2*>(&bfr[ni]) = *reinterpret_cast<const uint2*>(bp);
                *(reinterpret_cast<uint2*>(&bfr[ni]) + 1) = *reinterpret_cast<const uint2*>(bp + 4);
            }
            #pragma unroll
            for (int mi = 0; mi < 4; ++mi)
                #pragma unroll
                for (int ni = 0; ni < 2; ++ni)
                    acc[mi][ni] = __builtin_amdgcn_mfma_f32_16x16x32_bf16(
                        af[mi], bfr[ni], acc[mi][ni], 0, 0, 0);
        }
        __syncthreads();
    }

    // Epilogue: bias + ReLU into acc; store t to global.
    #pragma unroll
    for (int ni = 0; ni < 2; ++ni) {
        int col = w * 32 + ni * 16 + lr;
        float bn = bneigh[col];
        #pragma unroll
        for (int mi = 0; mi < 4; ++mi) {
            #pragma unroll
            for (int r = 0; r < 4; ++r) {
                float v = fmaxf(acc[mi][ni][r] + bn, 0.f);
                acc[mi][ni][r] = v;
                int grow = brow + mi * 16 + lq * 4 + r;
                if (grow < N_NODES) tout[(size_t)grow * FEAT + col] = v;
            }
        }
    }
    __syncthreads();   // phase-1 LDS dead

    // Stage WpT (48x128, zero-padded cols 40..47) + deposit t-tile into A2h.
    for (int i = tid; i < FEAT * CLS; i += 256) {
        int k = i / CLS, col = i - k * CLS;
        WpT[col * A2HSTR + k] = f2b(Wpred[i]);
    }
    for (int i = tid; i < 8 * FEAT; i += 256) {
        int k = i & 127, col = CLS + (i >> 7);
        WpT[col * A2HSTR + k] = 0;
    }
    #pragma unroll
    for (int ni = 0; ni < 2; ++ni) {
        int col = w * 32 + ni * 16 + lr;
        #pragma unroll
        for (int mi = 0; mi < 4; ++mi)
            #pragma unroll
            for (int r = 0; r < 4; ++r)
                A2h[(mi * 16 + lq * 4 + r) * A2HSTR + col] = f2b(acc[mi][ni][r]);
    }
    __syncthreads();

    // Phase 2: wave w -> rows [w*16, w*16+16).
    f32x4 oacc[3];
    #pragma unroll
    for (int j = 0; j < 3; ++j) oacc[j] = (f32x4){0.f, 0.f, 0.f, 0.f};
    #pragma unroll
    for (int ks = 0; ks < 4; ++ks) {
        short8 a2f, b2fr[3];
        *reinterpret_cast<uint4*>(&a2f) =
            *reinterpret_cast<const uint4*>(&A2h[(w * 16 + lr) * A2HSTR + ks * 32 + lq * 8]);
        #pragma unroll
        for (int cf = 0; cf < 3; ++cf)
            *reinterpret_cast<uint4*>(&b2fr[cf]) =
                *reinterpret_cast<const uint4*>(&WpT[(cf * 16 + lr) * A2HSTR + ks * 32 + lq * 8]);
        #pragma unroll
        for (int cf = 0; cf < 3; ++cf)
            oacc[cf] = __builtin_amdgcn_mfma_f32_16x16x32_bf16(a2f, b2fr[cf], oacc[cf], 0, 0, 0);
    }
    #pragma unroll
    for (int cf = 0; cf < 3; ++cf) {
        int col = cf * 16 + lr;
        if (col < CLS) {
            float bp = bpred[col];
            #pragma unroll
            for (int r = 0; r < 4; ++r) {
                int grow = brow + w * 16 + lq * 4 + r;
                if (grow < N_NODES)
                    outp[(size_t)grow * CLS + col] = oacc[cf][r] + bp;
            }
        }
    }
}

extern "C" void kernel_launch(void* const* d_in, const int* in_sizes, int n_in,
                              void* d_out, int out_size, void* d_ws, size_t ws_size,
                              hipStream_t stream) {
    const float* feat   = (const float*)d_in[0];
    const int*   src    = (const int*)d_in[1];
    const int*   dst    = (const int*)d_in[2];
    const float* Wself  = (const float*)d_in[3];
    const float* Wneigh = (const float*)d_in[4];
    const float* bneigh = (const float*)d_in[5];
    const float* Wpred  = (const float*)d_in[6];
    const float* bpred  = (const float*)d_in[7];

    // d_out layout: [ out : 100000*40 f32 | t : 100000*128 f32 ]
    float* obuf = (float*)d_out;
    float* tbuf = obuf + (size_t)N_NODES * CLS;

    int* deg     = (int*)d_ws;
    int* bsum    = deg + N_NODES;
    int* boff    = bsum + 512;
    int* rowptr  = boff + 512;
    int* cursor  = rowptr + (N_NODES + 1);
    int* csr_src = cursor + N_NODES;
    size_t int_bytes = ((3 * (size_t)N_NODES + 1025 + N_EDGES) * 4 + 255) & ~(size_t)255;
    unsigned short* featb = (unsigned short*)((char*)d_ws + int_bytes);
    unsigned short* hnb   = featb + (size_t)N_NODES * FEAT;
    size_t need = int_bytes + 2 * (size_t)N_NODES * FEAT * 2;
    bool full = ws_size >= need;

    (void)hipMemsetAsync(deg, 0, N_NODES * sizeof(int), stream);

    deg_kernel<<<(N_EDGES + 255) / 256, 256, 0, stream>>>(dst, deg);
    bsum_kernel<<<NBLK, 256, 0, stream>>>(deg, bsum);
    bscan_kernel<<<1, 512, 0, stream>>>(bsum, boff);
    rowptr_kernel<<<NBLK, 256, 0, stream>>>(deg, boff, rowptr, cursor);
    fill_kernel<<<(N_EDGES + 255) / 256, 256, 0, stream>>>(src, dst, cursor, csr_src);

    if (full) {
        feat2bf_kernel<<<(N_NODES * FEAT / 8 + 255) / 256, 256, 0, stream>>>(feat, featb);
        hnb_kernel<<<(N_NODES + 3) / 4, 256, 0, stream>>>(featb, rowptr, csr_src, hnb);
        tgemm_kernel<1><<<NB2, 256, 0, stream>>>(
            feat, nullptr, featb, hnb, Wself, Wneigh, bneigh, Wpred, bpred, tbuf, obuf);
    } else {
        float* hn = tbuf;
        hn_kernel<<<(N_NODES + 3) / 4, 256, 0, stream>>>(feat, rowptr, csr_src, hn);
        tgemm_kernel<0><<<NB2, 256, 0, stream>>>(
            feat, hn, nullptr, nullptr, Wself, Wneigh, bneigh, Wpred, bpred, tbuf, obuf);
    }
}

// Round 16
// 154.586 us; speedup vs baseline: 3.8907x; 1.0007x over previous
//
#include <hip/hip_runtime.h>
#include <hip/hip_bf16.h>

#define N_NODES 100000
#define N_EDGES 600000
#define FEAT 128
#define KTOT 256
#define CLS 40
#define TM 64
#define NB2 1563   // ceil(N_NODES/TM)
#define NBLK 391   // ceil(N_NODES/256)

typedef __attribute__((ext_vector_type(8))) short short8;
typedef __attribute__((ext_vector_type(4))) float f32x4;

__device__ __forceinline__ unsigned short f2b(float f) {
    __hip_bfloat16 h = __float2bfloat16(f);
    return *reinterpret_cast<unsigned short*>(&h);
}
__device__ __forceinline__ float b2f(unsigned int u16) {
    return __uint_as_float(u16 << 16);
}

// ---------- zero deg (replaces pathological 40us fillBuffer from hipMemsetAsync) ----------
__global__ void zero_kernel(int* __restrict__ p) {
    int i = blockIdx.x * 256 + threadIdx.x;
    if (i < N_NODES) p[i] = 0;
}

// ---------- CSR build ----------
__global__ void deg_kernel(const int* __restrict__ dst, int* __restrict__ deg) {
    int e = blockIdx.x * 256 + threadIdx.x;
    if (e < N_EDGES) atomicAdd(&deg[dst[e]], 1);
}

__global__ void bsum_kernel(const int* __restrict__ deg, int* __restrict__ bsum) {
    __shared__ int s[256];
    int gi = blockIdx.x * 256 + threadIdx.x;
    s[threadIdx.x] = (gi < N_NODES) ? deg[gi] : 0;
    __syncthreads();
    for (int st = 128; st > 0; st >>= 1) {
        if (threadIdx.x < st) s[threadIdx.x] += s[threadIdx.x + st];
        __syncthreads();
    }
    if (threadIdx.x == 0) bsum[blockIdx.x] = s[0];
}

__global__ void bscan_kernel(const int* __restrict__ bsum, int* __restrict__ boff) {
    __shared__ int s[512];
    int t = threadIdx.x;
    int v = (t < NBLK) ? bsum[t] : 0;
    s[t] = v;
    __syncthreads();
    for (int st = 1; st < 512; st <<= 1) {
        int add = (t >= st) ? s[t - st] : 0;
        __syncthreads();
        s[t] += add;
        __syncthreads();
    }
    if (t < NBLK) boff[t] = s[t] - v;
}

__global__ void rowptr_kernel(const int* __restrict__ deg,
                              const int* __restrict__ boff,
                              int* __restrict__ rowptr,
                              int* __restrict__ cursor) {
    __shared__ int s[256];
    int t = threadIdx.x;
    int gi = blockIdx.x * 256 + t;
    int v = (gi < N_NODES) ? deg[gi] : 0;
    s[t] = v;
    __syncthreads();
    for (int st = 1; st < 256; st <<= 1) {
        int add = (t >= st) ? s[t - st] : 0;
        __syncthreads();
        s[t] += add;
        __syncthreads();
    }
    if (gi < N_NODES) {
        int excl = boff[blockIdx.x] + s[t] - v;
        rowptr[gi] = excl;
        cursor[gi] = excl;
        if (gi == N_NODES - 1) rowptr[N_NODES] = excl + v;
    }
}

__global__ void fill_kernel(const int* __restrict__ src, const int* __restrict__ dst,
                            int* __restrict__ cursor, int* __restrict__ csr_src) {
    int e = blockIdx.x * 256 + threadIdx.x;
    if (e >= N_EDGES) return;
    int pos = atomicAdd(&cursor[dst[e]], 1);
    csr_src[pos] = src[e];
}

// ---------- feat f32 -> bf16 ----------
__global__ __launch_bounds__(256, 8)
void feat2bf_kernel(const float* __restrict__ f, unsigned short* __restrict__ o) {
    size_t i = ((size_t)blockIdx.x * 256 + threadIdx.x) * 8;
    float4 a = *reinterpret_cast<const float4*>(f + i);
    float4 b = *reinterpret_cast<const float4*>(f + i + 4);
    ushort4 p0, p1;
    p0.x = f2b(a.x); p0.y = f2b(a.y); p0.z = f2b(a.z); p0.w = f2b(a.w);
    p1.x = f2b(b.x); p1.y = f2b(b.y); p1.z = f2b(b.z); p1.w = f2b(b.w);
    uint4 q;
    q.x = (unsigned)p0.x | ((unsigned)p0.y << 16);
    q.y = (unsigned)p0.z | ((unsigned)p0.w << 16);
    q.z = (unsigned)p1.x | ((unsigned)p1.y << 16);
    q.w = (unsigned)p1.z | ((unsigned)p1.w << 16);
    *reinterpret_cast<uint4*>(o + i) = q;
}

// ---------- h_neigh gather bf16: one wave/node, ILP-4 ----------
__global__ __launch_bounds__(256, 8)
void hnb_kernel(const unsigned short* __restrict__ featb,
                const int* __restrict__ rowptr,
                const int* __restrict__ csr_src,
                unsigned short* __restrict__ hnb) {
    int node = blockIdx.x * 4 + (threadIdx.x >> 6);
    int lane = threadIdx.x & 63;
    if (node >= N_NODES) return;
    int r0 = rowptr[node], r1 = rowptr[node + 1];
    float sx = 0.f, sy = 0.f;
    int p = r0;
    for (; p + 4 <= r1; p += 4) {
        int nb0 = csr_src[p + 0];
        int nb1 = csr_src[p + 1];
        int nb2 = csr_src[p + 2];
        int nb3 = csr_src[p + 3];
        unsigned int v0 = *reinterpret_cast<const unsigned int*>(featb + (size_t)nb0 * FEAT + lane * 2);
        unsigned int v1 = *reinterpret_cast<const unsigned int*>(featb + (size_t)nb1 * FEAT + lane * 2);
        unsigned int v2 = *reinterpret_cast<const unsigned int*>(featb + (size_t)nb2 * FEAT + lane * 2);
        unsigned int v3 = *reinterpret_cast<const unsigned int*>(featb + (size_t)nb3 * FEAT + lane * 2);
        sx += (b2f(v0 & 0xffffu) + b2f(v1 & 0xffffu)) + (b2f(v2 & 0xffffu) + b2f(v3 & 0xffffu));
        sy += (b2f(v0 >> 16) + b2f(v1 >> 16)) + (b2f(v2 >> 16) + b2f(v3 >> 16));
    }
    if (p + 2 <= r1) {
        int nb0 = csr_src[p + 0];
        int nb1 = csr_src[p + 1];
        unsigned int v0 = *reinterpret_cast<const unsigned int*>(featb + (size_t)nb0 * FEAT + lane * 2);
        unsigned int v1 = *reinterpret_cast<const unsigned int*>(featb + (size_t)nb1 * FEAT + lane * 2);
        sx += b2f(v0 & 0xffffu) + b2f(v1 & 0xffffu);
        sy += b2f(v0 >> 16) + b2f(v1 >> 16);
        p += 2;
    }
    if (p < r1) {
        int nb = csr_src[p];
        unsigned int v = *reinterpret_cast<const unsigned int*>(featb + (size_t)nb * FEAT + lane * 2);
        sx += b2f(v & 0xffffu);
        sy += b2f(v >> 16);
    }
    float inv = 1.0f / fmaxf((float)(r1 - r0), 1.0f);
    unsigned int o = (unsigned)f2b(sx * inv) | ((unsigned)f2b(sy * inv) << 16);
    *reinterpret_cast<unsigned int*>(hnb + (size_t)node * FEAT + lane * 2) = o;
}

// f32 fallback gather (small-ws tier)
__global__ __launch_bounds__(256, 4)
void hn_kernel(const float* __restrict__ feat,
               const int* __restrict__ rowptr,
               const int* __restrict__ csr_src,
               float* __restrict__ hn) {
    int node = blockIdx.x * 4 + (threadIdx.x >> 6);
    int lane = threadIdx.x & 63;
    if (node >= N_NODES) return;
    int r0 = rowptr[node], r1 = rowptr[node + 1];
    float sx = 0.f, sy = 0.f;
    for (int p = r0; p < r1; ++p) {
        int nb = csr_src[p];
        float2 f = *reinterpret_cast<const float2*>(feat + (size_t)nb * FEAT + lane * 2);
        sx += f.x; sy += f.y;
    }
    float inv = 1.0f / fmaxf((float)(r1 - r0), 1.0f);
    float2 o; o.x = sx * inv; o.y = sy * inv;
    *reinterpret_cast<float2*>(hn + (size_t)node * FEAT + lane * 2) = o;
}

// ---------- fused: t = relu([feat|hn]@[Ws;Wn]+bn);  out = t@Wp + bp ----------
// 64x128 tile, BK=64 (4 K-steps), 4 waves each 64x32.
// LDS: Asb [0,9216) | Bsb [9216,26624) || phase2: A2h [0,19456) | WpT [19456,34048)
#define ASTR 72
#define BSTR 68
#define A2HSTR 152
template <int BF16IN>
__global__ __launch_bounds__(256, 4)
void tgemm_kernel(const float* __restrict__ feat,
                  const float* __restrict__ hn,
                  const unsigned short* __restrict__ featb,
                  const unsigned short* __restrict__ hnb,
                  const float* __restrict__ Wself,
                  const float* __restrict__ Wneigh,
                  const float* __restrict__ bneigh,
                  const float* __restrict__ Wpred,
                  const float* __restrict__ bpred,
                  float* __restrict__ tout,
                  float* __restrict__ outp) {
    __shared__ __align__(16) char smem[34048];
    unsigned short* Asb = (unsigned short*)smem;            // [64][ASTR]
    unsigned short* Bsb = (unsigned short*)(smem + 9216);   // [128][BSTR]
    unsigned short* A2h = (unsigned short*)smem;            // [64][A2HSTR]
    unsigned short* WpT = (unsigned short*)(smem + 19456);  // [48][A2HSTR]

    int tid  = threadIdx.x;
    int lane = tid & 63;
    int w    = tid >> 6;        // wave 0..3 -> cols [w*32, w*32+32)
    int lr   = lane & 15;
    int lq   = lane >> 4;
    int brow = blockIdx.x * TM;

    f32x4 acc[4][2];
    #pragma unroll
    for (int i = 0; i < 4; ++i)
        #pragma unroll
        for (int j = 0; j < 2; ++j) acc[i][j] = (f32x4){0.f, 0.f, 0.f, 0.f};

    for (int k0 = 0; k0 < KTOT; k0 += 64) {
        // ---- Stage A: 64 rows x 64 k ----
        if (BF16IN) {
            #pragma unroll
            for (int i = 0; i < 2; ++i) {
                int u = tid + 256 * i;      // 0..511
                int row = u >> 3;           // 0..63
                int c8 = u & 7;             // 8-bf16 group
                int node = brow + row;
                uint4 v = {0u, 0u, 0u, 0u};
                if (node < N_NODES) {
                    const unsigned short* sp = (k0 < FEAT)
                        ? featb + (size_t)node * FEAT + k0
                        : hnb   + (size_t)node * FEAT + (k0 - FEAT);
                    v = *reinterpret_cast<const uint4*>(sp + c8 * 8);
                }
                *reinterpret_cast<uint4*>(&Asb[row * ASTR + c8 * 8]) = v;
            }
        } else {
            #pragma unroll
            for (int i = 0; i < 4; ++i) {
                int u   = tid + 256 * i;    // 0..1023
                int row = u >> 4;           // 0..63
                int c4  = u & 15;
                int node = brow + row;
                int k = k0 + c4 * 4;
                float4 v = make_float4(0.f, 0.f, 0.f, 0.f);
                if (node < N_NODES) {
                    const float* base = (k < FEAT)
                        ? feat + (size_t)node * FEAT + k
                        : hn   + (size_t)node * FEAT + (k - FEAT);
                    v = *reinterpret_cast<const float4*>(base);
                }
                ushort4 p;
                p.x = f2b(v.x); p.y = f2b(v.y); p.z = f2b(v.z); p.w = f2b(v.w);
                *reinterpret_cast<ushort4*>(&Asb[row * ASTR + c4 * 4]) = p;
            }
        }
        // ---- Stage B transposed: 128 cols x 64 k from f32 W ----
        #pragma unroll
        for (int i = 0; i < 8; ++i) {
            int u  = tid + 256 * i;         // 0..2047
            int n  = u & 127;
            int kq = u >> 7;                // 0..15
            int k  = k0 + kq * 4;
            const float* base = ((k0 < FEAT) ? (Wself + (size_t)k * FEAT)
                                             : (Wneigh + (size_t)(k - FEAT) * FEAT)) + n;
            ushort4 p;
            p.x = f2b(base[0]);
            p.y = f2b(base[FEAT]);
            p.z = f2b(base[2 * FEAT]);
            p.w = f2b(base[3 * FEAT]);
            *reinterpret_cast<ushort4*>(&Bsb[n * BSTR + kq * 4]) = p;
        }
        __syncthreads();

        #pragma unroll
        for (int ks = 0; ks < 2; ++ks) {
            short8 af[4], bfr[2];
            #pragma unroll
            for (int mi = 0; mi < 4; ++mi) {
                int row = mi * 16 + lr;
                *reinterpret_cast<uint4*>(&af[mi]) =
                    *reinterpret_cast<const uint4*>(&Asb[row * ASTR + ks * 32 + lq * 8]);
            }
            #pragma unroll
            for (int ni = 0; ni < 2; ++ni) {
                int col = w * 32 + ni * 16 + lr;
                const unsigned short* bp = &Bsb[col * BSTR + ks * 32 + lq * 8];
                *reinterpret_cast<uint2*>(&bfr[ni]) = *reinterpret_cast<const uint2*>(bp);
                *(reinterpret_cast<uint2*>(&bfr[ni]) + 1) = *reinterpret_cast<const uint2*>(bp + 4);
            }
            #pragma unroll
            for (int mi = 0; mi < 4; ++mi)
                #pragma unroll
                for (int ni = 0; ni < 2; ++ni)
                    acc[mi][ni] = __builtin_amdgcn_mfma_f32_16x16x32_bf16(
                        af[mi], bfr[ni], acc[mi][ni], 0, 0, 0);
        }
        __syncthreads();
    }

    // Epilogue: bias + ReLU into acc; store t to global.
    #pragma unroll
    for (int ni = 0; ni < 2; ++ni) {
        int col = w * 32 + ni * 16 + lr;
        float bn = bneigh[col];
        #pragma unroll
        for (int mi = 0; mi < 4; ++mi) {
            #pragma unroll
            for (int r = 0; r < 4; ++r) {
                float v = fmaxf(acc[mi][ni][r] + bn, 0.f);
                acc[mi][ni][r] = v;
                int grow = brow + mi * 16 + lq * 4 + r;
                if (grow < N_NODES) tout[(size_t)grow * FEAT + col] = v;
            }
        }
    }
    __syncthreads();   // phase-1 LDS dead

    // Stage WpT (48x128, zero-padded cols 40..47) + deposit t-tile into A2h.
    for (int i = tid; i < FEAT * CLS; i += 256) {
        int k = i / CLS, col = i - k * CLS;
        WpT[col * A2HSTR + k] = f2b(Wpred[i]);
    }
    for (int i = tid; i < 8 * FEAT; i += 256) {
        int k = i & 127, col = CLS + (i >> 7);
        WpT[col * A2HSTR + k] = 0;
    }
    #pragma unroll
    for (int ni = 0; ni < 2; ++ni) {
        int col = w * 32 + ni * 16 + lr;
        #pragma unroll
        for (int mi = 0; mi < 4; ++mi)
            #pragma unroll
            for (int r = 0; r < 4; ++r)
                A2h[(mi * 16 + lq * 4 + r) * A2HSTR + col] = f2b(acc[mi][ni][r]);
    }
    __syncthreads();

    // Phase 2: wave w -> rows [w*16, w*16+16).
    f32x4 oacc[3];
    #pragma unroll
    for (int j = 0; j < 3; ++j) oacc[j] = (f32x4){0.f, 0.f, 0.f, 0.f};
    #pragma unroll
    for (int ks = 0; ks < 4; ++ks) {
        short8 a2f, b2fr[3];
        *reinterpret_cast<uint4*>(&a2f) =
            *reinterpret_cast<const uint4*>(&A2h[(w * 16 + lr) * A2HSTR + ks * 32 + lq * 8]);
        #pragma unroll
        for (int cf = 0; cf < 3; ++cf)
            *reinterpret_cast<uint4*>(&b2fr[cf]) =
                *reinterpret_cast<const uint4*>(&WpT[(cf * 16 + lr) * A2HSTR + ks * 32 + lq * 8]);
        #pragma unroll
        for (int cf = 0; cf < 3; ++cf)
            oacc[cf] = __builtin_amdgcn_mfma_f32_16x16x32_bf16(a2f, b2fr[cf], oacc[cf], 0, 0, 0);
    }
    #pragma unroll
    for (int cf = 0; cf < 3; ++cf) {
        int col = cf * 16 + lr;
        if (col < CLS) {
            float bp = bpred[col];
            #pragma unroll
            for (int r = 0; r < 4; ++r) {
                int grow = brow + w * 16 + lq * 4 + r;
                if (grow < N_NODES)
                    outp[(size_t)grow * CLS + col] = oacc[cf][r] + bp;
            }
        }
    }
}

extern "C" void kernel_launch(void* const* d_in, const int* in_sizes, int n_in,
                              void* d_out, int out_size, void* d_ws, size_t ws_size,
                              hipStream_t stream) {
    const float* feat   = (const float*)d_in[0];
    const int*   src    = (const int*)d_in[1];
    const int*   dst    = (const int*)d_in[2];
    const float* Wself  = (const float*)d_in[3];
    const float* Wneigh = (const float*)d_in[4];
    const float* bneigh = (const float*)d_in[5];
    const float* Wpred  = (const float*)d_in[6];
    const float* bpred  = (const float*)d_in[7];

    // d_out layout: [ out : 100000*40 f32 | t : 100000*128 f32 ]
    float* obuf = (float*)d_out;
    float* tbuf = obuf + (size_t)N_NODES * CLS;

    int* deg     = (int*)d_ws;
    int* bsum    = deg + N_NODES;
    int* boff    = bsum + 512;
    int* rowptr  = boff + 512;
    int* cursor  = rowptr + (N_NODES + 1);
    int* csr_src = cursor + N_NODES;
    size_t int_bytes = ((3 * (size_t)N_NODES + 1025 + N_EDGES) * 4 + 255) & ~(size_t)255;
    unsigned short* featb = (unsigned short*)((char*)d_ws + int_bytes);
    unsigned short* hnb   = featb + (size_t)N_NODES * FEAT;
    size_t need = int_bytes + 2 * (size_t)N_NODES * FEAT * 2;
    bool full = ws_size >= need;

    zero_kernel<<<NBLK, 256, 0, stream>>>(deg);

    deg_kernel<<<(N_EDGES + 255) / 256, 256, 0, stream>>>(dst, deg);
    bsum_kernel<<<NBLK, 256, 0, stream>>>(deg, bsum);
    bscan_kernel<<<1, 512, 0, stream>>>(bsum, boff);
    rowptr_kernel<<<NBLK, 256, 0, stream>>>(deg, boff, rowptr, cursor);
    fill_kernel<<<(N_EDGES + 255) / 256, 256, 0, stream>>>(src, dst, cursor, csr_src);

    if (full) {
        feat2bf_kernel<<<(N_NODES * FEAT / 8 + 255) / 256, 256, 0, stream>>>(feat, featb);
        hnb_kernel<<<(N_NODES + 3) / 4, 256, 0, stream>>>(featb, rowptr, csr_src, hnb);
        tgemm_kernel<1><<<NB2, 256, 0, stream>>>(
            feat, nullptr, featb, hnb, Wself, Wneigh, bneigh, Wpred, bpred, tbuf, obuf);
    } else {
        float* hn = tbuf;
        hn_kernel<<<(N_NODES + 3) / 4, 256, 0, stream>>>(feat, rowptr, csr_src, hn);
        tgemm_kernel<0><<<NB2, 256, 0, stream>>>(
            feat, hn, nullptr, nullptr, Wself, Wneigh, bneigh, Wpred, bpred, tbuf, obuf);
    }
}

// Round 17
// 145.006 us; speedup vs baseline: 4.1478x; 1.0661x over previous
//
#include <hip/hip_runtime.h>
#include <hip/hip_bf16.h>

#define N_NODES 100000
#define N_EDGES 600000
#define FEAT 128
#define KTOT 256
#define CLS 40
#define TM 64
#define NB2 1563   // ceil(N_NODES/TM)
#define NBLK 391   // ceil(N_NODES/256)
#define DEG_B 2344 // ceil(N_EDGES/256)
#define F2B_B 6250 // N_NODES*FEAT/8/256
#define WC_B 38    // (128*256 + 48*128) / 1024

typedef __attribute__((ext_vector_type(8))) short short8;
typedef __attribute__((ext_vector_type(4))) float f32x4;

__device__ __forceinline__ unsigned short f2b(float f) {
    __hip_bfloat16 h = __float2bfloat16(f);
    return *reinterpret_cast<unsigned short*>(&h);
}
__device__ __forceinline__ float b2f(unsigned int u16) {
    return __uint_as_float(u16 << 16);
}

// ---------- zero deg ----------
__global__ void zero_kernel(int* __restrict__ p) {
    int i = blockIdx.x * 256 + threadIdx.x;
    if (i < N_NODES) p[i] = 0;
}

// ---------- combo: deg-count || feat->bf16 || weight pre-convert ----------
__global__ __launch_bounds__(256, 8)
void combo_kernel(const int* __restrict__ dst, int* __restrict__ deg,
                  const float* __restrict__ feat, unsigned short* __restrict__ featb,
                  const float* __restrict__ Wself, const float* __restrict__ Wneigh,
                  const float* __restrict__ Wpred,
                  unsigned short* __restrict__ WbT, unsigned short* __restrict__ WpTb) {
    int b = blockIdx.x;
    int t = threadIdx.x;
    if (b < DEG_B) {
        int e = b * 256 + t;
        if (e < N_EDGES) atomicAdd(&deg[dst[e]], 1);
    } else if (b < DEG_B + F2B_B) {
        size_t i = ((size_t)(b - DEG_B) * 256 + t) * 8;
        float4 a = *reinterpret_cast<const float4*>(feat + i);
        float4 c = *reinterpret_cast<const float4*>(feat + i + 4);
        uint4 q;
        q.x = (unsigned)f2b(a.x) | ((unsigned)f2b(a.y) << 16);
        q.y = (unsigned)f2b(a.z) | ((unsigned)f2b(a.w) << 16);
        q.z = (unsigned)f2b(c.x) | ((unsigned)f2b(c.y) << 16);
        q.w = (unsigned)f2b(c.z) | ((unsigned)f2b(c.w) << 16);
        *reinterpret_cast<uint4*>(featb + i) = q;
    } else {
        // weight conversion: WbT[n][k] (128x256) then WpTb[col][k] (48x128, pad 0)
        int i = (b - DEG_B - F2B_B) * 1024 + t * 4;
        ushort4 p;
        if (i < 128 * 256) {
            int n = i >> 8, k = i & 255;
            #pragma unroll
            for (int j = 0; j < 4; ++j) {
                int kj = k + j;
                float v = (kj < FEAT) ? Wself[(size_t)kj * FEAT + n]
                                      : Wneigh[(size_t)(kj - FEAT) * FEAT + n];
                ((unsigned short*)&p)[j] = f2b(v);
            }
            *reinterpret_cast<ushort4*>(WbT + i) = p;
        } else {
            int i2 = i - 128 * 256;   // < 6144
            int col = i2 >> 7, k = i2 & 127;
            #pragma unroll
            for (int j = 0; j < 4; ++j) {
                float v = (col < CLS) ? Wpred[(size_t)(k + j) * CLS + col] : 0.f;
                ((unsigned short*)&p)[j] = f2b(v);
            }
            *reinterpret_cast<ushort4*>(WpTb + i2) = p;
        }
    }
}

// ---------- bsum ----------
__global__ void bsum_kernel(const int* __restrict__ deg, int* __restrict__ bsum) {
    __shared__ int s[256];
    int gi = blockIdx.x * 256 + threadIdx.x;
    s[threadIdx.x] = (gi < N_NODES) ? deg[gi] : 0;
    __syncthreads();
    for (int st = 128; st > 0; st >>= 1) {
        if (threadIdx.x < st) s[threadIdx.x] += s[threadIdx.x + st];
        __syncthreads();
    }
    if (threadIdx.x == 0) bsum[blockIdx.x] = s[0];
}

// ---------- rowptr with inline block-offset reduction (bscan folded in) ----------
__global__ void rowptr_kernel(const int* __restrict__ deg,
                              const int* __restrict__ bsum,
                              int* __restrict__ rowptr,
                              int* __restrict__ cursor) {
    __shared__ int sb[256];
    __shared__ int s[256];
    __shared__ int boff;
    int t = threadIdx.x;
    int bid = blockIdx.x;
    // sum of bsum[j] for j < bid
    int v1 = (t < NBLK && t < bid) ? bsum[t] : 0;
    int j2 = t + 256;
    int v2 = (j2 < NBLK && j2 < bid) ? bsum[j2] : 0;
    sb[t] = v1 + v2;
    __syncthreads();
    for (int st = 128; st > 0; st >>= 1) {
        if (t < st) sb[t] += sb[t + st];
        __syncthreads();
    }
    if (t == 0) boff = sb[0];
    // per-element inclusive scan within block
    int gi = bid * 256 + t;
    int v = (gi < N_NODES) ? deg[gi] : 0;
    s[t] = v;
    __syncthreads();
    for (int st = 1; st < 256; st <<= 1) {
        int add = (t >= st) ? s[t - st] : 0;
        __syncthreads();
        s[t] += add;
        __syncthreads();
    }
    if (gi < N_NODES) {
        int excl = boff + s[t] - v;
        rowptr[gi] = excl;
        cursor[gi] = excl;
        if (gi == N_NODES - 1) rowptr[N_NODES] = excl + v;
    }
}

__global__ void fill_kernel(const int* __restrict__ src, const int* __restrict__ dst,
                            int* __restrict__ cursor, int* __restrict__ csr_src) {
    int e = blockIdx.x * 256 + threadIdx.x;
    if (e >= N_EDGES) return;
    int pos = atomicAdd(&cursor[dst[e]], 1);
    csr_src[pos] = src[e];
}

// ---------- h_neigh gather bf16: one wave/node, ILP-4 ----------
__global__ __launch_bounds__(256, 8)
void hnb_kernel(const unsigned short* __restrict__ featb,
                const int* __restrict__ rowptr,
                const int* __restrict__ csr_src,
                unsigned short* __restrict__ hnb) {
    int node = blockIdx.x * 4 + (threadIdx.x >> 6);
    int lane = threadIdx.x & 63;
    if (node >= N_NODES) return;
    int r0 = rowptr[node], r1 = rowptr[node + 1];
    float sx = 0.f, sy = 0.f;
    int p = r0;
    for (; p + 4 <= r1; p += 4) {
        int nb0 = csr_src[p + 0];
        int nb1 = csr_src[p + 1];
        int nb2 = csr_src[p + 2];
        int nb3 = csr_src[p + 3];
        unsigned int v0 = *reinterpret_cast<const unsigned int*>(featb + (size_t)nb0 * FEAT + lane * 2);
        unsigned int v1 = *reinterpret_cast<const unsigned int*>(featb + (size_t)nb1 * FEAT + lane * 2);
        unsigned int v2 = *reinterpret_cast<const unsigned int*>(featb + (size_t)nb2 * FEAT + lane * 2);
        unsigned int v3 = *reinterpret_cast<const unsigned int*>(featb + (size_t)nb3 * FEAT + lane * 2);
        sx += (b2f(v0 & 0xffffu) + b2f(v1 & 0xffffu)) + (b2f(v2 & 0xffffu) + b2f(v3 & 0xffffu));
        sy += (b2f(v0 >> 16) + b2f(v1 >> 16)) + (b2f(v2 >> 16) + b2f(v3 >> 16));
    }
    if (p + 2 <= r1) {
        int nb0 = csr_src[p + 0];
        int nb1 = csr_src[p + 1];
        unsigned int v0 = *reinterpret_cast<const unsigned int*>(featb + (size_t)nb0 * FEAT + lane * 2);
        unsigned int v1 = *reinterpret_cast<const unsigned int*>(featb + (size_t)nb1 * FEAT + lane * 2);
        sx += b2f(v0 & 0xffffu) + b2f(v1 & 0xffffu);
        sy += b2f(v0 >> 16) + b2f(v1 >> 16);
        p += 2;
    }
    if (p < r1) {
        int nb = csr_src[p];
        unsigned int v = *reinterpret_cast<const unsigned int*>(featb + (size_t)nb * FEAT + lane * 2);
        sx += b2f(v & 0xffffu);
        sy += b2f(v >> 16);
    }
    float inv = 1.0f / fmaxf((float)(r1 - r0), 1.0f);
    unsigned int o = (unsigned)f2b(sx * inv) | ((unsigned)f2b(sy * inv) << 16);
    *reinterpret_cast<unsigned int*>(hnb + (size_t)node * FEAT + lane * 2) = o;
}

// f32 fallback gather (small-ws tier)
__global__ __launch_bounds__(256, 4)
void hn_kernel(const float* __restrict__ feat,
               const int* __restrict__ rowptr,
               const int* __restrict__ csr_src,
               float* __restrict__ hn) {
    int node = blockIdx.x * 4 + (threadIdx.x >> 6);
    int lane = threadIdx.x & 63;
    if (node >= N_NODES) return;
    int r0 = rowptr[node], r1 = rowptr[node + 1];
    float sx = 0.f, sy = 0.f;
    for (int p = r0; p < r1; ++p) {
        int nb = csr_src[p];
        float2 f = *reinterpret_cast<const float2*>(feat + (size_t)nb * FEAT + lane * 2);
        sx += f.x; sy += f.y;
    }
    float inv = 1.0f / fmaxf((float)(r1 - r0), 1.0f);
    float2 o; o.x = sx * inv; o.y = sy * inv;
    *reinterpret_cast<float2*>(hn + (size_t)node * FEAT + lane * 2) = o;
}

// ---------- fused: t = relu([feat|hn]@[Ws;Wn]+bn);  out = t@Wp + bp ----------
// 64x128 tile, BK=64 (4 K-steps), 4 waves each 64x32. B & Wp staged from
// pre-converted bf16 (WbT [128][256], WpTb [48][128]) — copies, no cvt.
// LDS: Asb [0,9216) | Bsb [9216,26624) || phase2: A2h [0,19456) | WpT [19456,34048)
#define ASTR 72
#define BSTR 68
#define A2HSTR 152
template <int BF16IN>
__global__ __launch_bounds__(256, 4)
void tgemm_kernel(const float* __restrict__ feat,
                  const float* __restrict__ hn,
                  const unsigned short* __restrict__ featb,
                  const unsigned short* __restrict__ hnb,
                  const unsigned short* __restrict__ WbT,
                  const unsigned short* __restrict__ WpTb,
                  const float* __restrict__ bneigh,
                  const float* __restrict__ bpred,
                  float* __restrict__ tout,
                  float* __restrict__ outp) {
    __shared__ __align__(16) char smem[34048];
    unsigned short* Asb = (unsigned short*)smem;            // [64][ASTR]
    unsigned short* Bsb = (unsigned short*)(smem + 9216);   // [128][BSTR]
    unsigned short* A2h = (unsigned short*)smem;            // [64][A2HSTR]
    unsigned short* WpT = (unsigned short*)(smem + 19456);  // [48][A2HSTR]

    int tid  = threadIdx.x;
    int lane = tid & 63;
    int w    = tid >> 6;        // wave 0..3 -> cols [w*32, w*32+32)
    int lr   = lane & 15;
    int lq   = lane >> 4;
    int brow = blockIdx.x * TM;

    f32x4 acc[4][2];
    #pragma unroll
    for (int i = 0; i < 4; ++i)
        #pragma unroll
        for (int j = 0; j < 2; ++j) acc[i][j] = (f32x4){0.f, 0.f, 0.f, 0.f};

    for (int k0 = 0; k0 < KTOT; k0 += 64) {
        // ---- Stage A: 64 rows x 64 k ----
        if (BF16IN) {
            #pragma unroll
            for (int i = 0; i < 2; ++i) {
                int u = tid + 256 * i;      // 0..511
                int row = u >> 3;           // 0..63
                int c8 = u & 7;
                int node = brow + row;
                uint4 v = {0u, 0u, 0u, 0u};
                if (node < N_NODES) {
                    const unsigned short* sp = (k0 < FEAT)
                        ? featb + (size_t)node * FEAT + k0
                        : hnb   + (size_t)node * FEAT + (k0 - FEAT);
                    v = *reinterpret_cast<const uint4*>(sp + c8 * 8);
                }
                *reinterpret_cast<uint4*>(&Asb[row * ASTR + c8 * 8]) = v;
            }
        } else {
            #pragma unroll
            for (int i = 0; i < 4; ++i) {
                int u   = tid + 256 * i;
                int row = u >> 4;
                int c4  = u & 15;
                int node = brow + row;
                int k = k0 + c4 * 4;
                float4 v = make_float4(0.f, 0.f, 0.f, 0.f);
                if (node < N_NODES) {
                    const float* base = (k < FEAT)
                        ? feat + (size_t)node * FEAT + k
                        : hn   + (size_t)node * FEAT + (k - FEAT);
                    v = *reinterpret_cast<const float4*>(base);
                }
                ushort4 p;
                p.x = f2b(v.x); p.y = f2b(v.y); p.z = f2b(v.z); p.w = f2b(v.w);
                *reinterpret_cast<ushort4*>(&Asb[row * ASTR + c4 * 4]) = p;
            }
        }
        // ---- Stage B: copy from pre-converted WbT [n][k] ----
        #pragma unroll
        for (int i = 0; i < 4; ++i) {
            int u = tid + 256 * i;          // 0..1023 = 128 n x 8 groups
            int n = u >> 3;
            int g = u & 7;
            *reinterpret_cast<uint4*>(&Bsb[n * BSTR + g * 8]) =
                *reinterpret_cast<const uint4*>(&WbT[(size_t)n * KTOT + k0 + g * 8]);
        }
        __syncthreads();

        #pragma unroll
        for (int ks = 0; ks < 2; ++ks) {
            short8 af[4], bfr[2];
            #pragma unroll
            for (int mi = 0; mi < 4; ++mi) {
                int row = mi * 16 + lr;
                *reinterpret_cast<uint4*>(&af[mi]) =
                    *reinterpret_cast<const uint4*>(&Asb[row * ASTR + ks * 32 + lq * 8]);
            }
            #pragma unroll
            for (int ni = 0; ni < 2; ++ni) {
                int col = w * 32 + ni * 16 + lr;
                const unsigned short* bp = &Bsb[col * BSTR + ks * 32 + lq * 8];
                *reinterpret_cast<uint2*>(&bfr[ni]) = *reinterpret_cast<const uint2*>(bp);
                *(reinterpret_cast<uint2*>(&bfr[ni]) + 1) = *reinterpret_cast<const uint2*>(bp + 4);
            }
            #pragma unroll
            for (int mi = 0; mi < 4; ++mi)
                #pragma unroll
                for (int ni = 0; ni < 2; ++ni)
                    acc[mi][ni] = __builtin_amdgcn_mfma_f32_16x16x32_bf16(
                        af[mi], bfr[ni], acc[mi][ni], 0, 0, 0);
        }
        __syncthreads();
    }

    // Epilogue: bias + ReLU into acc; store t to global.
    #pragma unroll
    for (int ni = 0; ni < 2; ++ni) {
        int col = w * 32 + ni * 16 + lr;
        float bn = bneigh[col];
        #pragma unroll
        for (int mi = 0; mi < 4; ++mi) {
            #pragma unroll
            for (int r = 0; r < 4; ++r) {
                float v = fmaxf(acc[mi][ni][r] + bn, 0.f);
                acc[mi][ni][r] = v;
                int grow = brow + mi * 16 + lq * 4 + r;
                if (grow < N_NODES) tout[(size_t)grow * FEAT + col] = v;
            }
        }
    }
    __syncthreads();   // phase-1 LDS dead

    // Stage WpT (copy from pre-converted WpTb) + deposit t-tile into A2h.
    #pragma unroll
    for (int i = 0; i < 3; ++i) {
        int u = tid + 256 * i;              // 0..767 = 48 cols x 16 groups
        int col = u >> 4;
        int g = u & 15;
        *reinterpret_cast<uint4*>(&WpT[col * A2HSTR + g * 8]) =
            *reinterpret_cast<const uint4*>(&WpTb[col * FEAT + g * 8]);
    }
    #pragma unroll
    for (int ni = 0; ni < 2; ++ni) {
        int col = w * 32 + ni * 16 + lr;
        #pragma unroll
        for (int mi = 0; mi < 4; ++mi)
            #pragma unroll
            for (int r = 0; r < 4; ++r)
                A2h[(mi * 16 + lq * 4 + r) * A2HSTR + col] = f2b(acc[mi][ni][r]);
    }
    __syncthreads();

    // Phase 2: wave w -> rows [w*16, w*16+16).
    f32x4 oacc[3];
    #pragma unroll
    for (int j = 0; j < 3; ++j) oacc[j] = (f32x4){0.f, 0.f, 0.f, 0.f};
    #pragma unroll
    for (int ks = 0; ks < 4; ++ks) {
        short8 a2f, b2fr[3];
        *reinterpret_cast<uint4*>(&a2f) =
            *reinterpret_cast<const uint4*>(&A2h[(w * 16 + lr) * A2HSTR + ks * 32 + lq * 8]);
        #pragma unroll
        for (int cf = 0; cf < 3; ++cf)
            *reinterpret_cast<uint4*>(&b2fr[cf]) =
                *reinterpret_cast<const uint4*>(&WpT[(cf * 16 + lr) * A2HSTR + ks * 32 + lq * 8]);
        #pragma unroll
        for (int cf = 0; cf < 3; ++cf)
            oacc[cf] = __builtin_amdgcn_mfma_f32_16x16x32_bf16(a2f, b2fr[cf], oacc[cf], 0, 0, 0);
    }
    #pragma unroll
    for (int cf = 0; cf < 3; ++cf) {
        int col = cf * 16 + lr;
        if (col < CLS) {
            float bp = bpred[col];
            #pragma unroll
            for (int r = 0; r < 4; ++r) {
                int grow = brow + w * 16 + lq * 4 + r;
                if (grow < N_NODES)
                    outp[(size_t)grow * CLS + col] = oacc[cf][r] + bp;
            }
        }
    }
}

extern "C" void kernel_launch(void* const* d_in, const int* in_sizes, int n_in,
                              void* d_out, int out_size, void* d_ws, size_t ws_size,
                              hipStream_t stream) {
    const float* feat   = (const float*)d_in[0];
    const int*   src    = (const int*)d_in[1];
    const int*   dst    = (const int*)d_in[2];
    const float* Wself  = (const float*)d_in[3];
    const float* Wneigh = (const float*)d_in[4];
    const float* bneigh = (const float*)d_in[5];
    const float* Wpred  = (const float*)d_in[6];
    const float* bpred  = (const float*)d_in[7];

    // d_out layout: [ out : 100000*40 f32 | t : 100000*128 f32 ]
    float* obuf = (float*)d_out;
    float* tbuf = obuf + (size_t)N_NODES * CLS;

    // ws: ints | WbT (64KB) | WpTb (12KB) | featb | hnb
    int* deg     = (int*)d_ws;
    int* bsum    = deg + N_NODES;
    int* rowptr  = bsum + 512;
    int* cursor  = rowptr + (N_NODES + 1);
    int* csr_src = cursor + N_NODES;
    size_t int_bytes = ((3 * (size_t)N_NODES + 513 + N_EDGES) * 4 + 255) & ~(size_t)255;
    unsigned short* WbT   = (unsigned short*)((char*)d_ws + int_bytes);
    unsigned short* WpTb  = WbT + 128 * KTOT;
    unsigned short* featb = WpTb + 48 * FEAT;
    unsigned short* hnb   = featb + (size_t)N_NODES * FEAT;
    size_t need_full = int_bytes + (128 * KTOT + 48 * FEAT) * 2
                     + 2 * (size_t)N_NODES * FEAT * 2;
    bool full = ws_size >= need_full;

    zero_kernel<<<NBLK, 256, 0, stream>>>(deg);
    combo_kernel<<<DEG_B + F2B_B + WC_B, 256, 0, stream>>>(
        dst, deg, feat, featb, Wself, Wneigh, Wpred, WbT, WpTb);
    bsum_kernel<<<NBLK, 256, 0, stream>>>(deg, bsum);
    rowptr_kernel<<<NBLK, 256, 0, stream>>>(deg, bsum, rowptr, cursor);
    fill_kernel<<<DEG_B, 256, 0, stream>>>(src, dst, cursor, csr_src);

    if (full) {
        hnb_kernel<<<(N_NODES + 3) / 4, 256, 0, stream>>>(featb, rowptr, csr_src, hnb);
        tgemm_kernel<1><<<NB2, 256, 0, stream>>>(
            feat, nullptr, featb, hnb, WbT, WpTb, bneigh, bpred, tbuf, obuf);
    } else {
        float* hn = tbuf;
        hn_kernel<<<(N_NODES + 3) / 4, 256, 0, stream>>>(feat, rowptr, csr_src, hn);
        tgemm_kernel<0><<<NB2, 256, 0, stream>>>(
            feat, hn, nullptr, nullptr, WbT, WpTb, bneigh, bpred, tbuf, obuf);
    }
}